// Round 6
// baseline (394.328 us; speedup 1.0000x reference)
//
#include <hip/hip_runtime.h>
#include <cstddef>

#define CC 128  // channels

// ===========================================================================
// CSR build: histogram -> 3-kernel parallel scan -> fill
// ===========================================================================

__global__ __launch_bounds__(256) void hist_rows(
    const int* __restrict__ row, int* __restrict__ counts, int E)
{
    const int e = blockIdx.x * 256 + threadIdx.x;
    if (e < E) atomicAdd(counts + row[e], 1);
}

// Per-block sum of 256 counts -> bsum[block]
__global__ __launch_bounds__(256) void scan_block_reduce(
    const int* __restrict__ counts, int* __restrict__ bsum, int N)
{
    __shared__ int s[256];
    const int t = threadIdx.x;
    const int idx = blockIdx.x * 256 + t;
    s[t] = (idx < N) ? counts[idx] : 0;
    __syncthreads();
    #pragma unroll
    for (int off = 128; off > 0; off >>= 1) {
        if (t < off) s[t] += s[t + off];
        __syncthreads();
    }
    if (t == 0) bsum[blockIdx.x] = s[0];
}

// Exclusive scan of NB (<=256) block sums, single block.
__global__ __launch_bounds__(256) void scan_bsum(
    const int* __restrict__ bsum, int* __restrict__ bpre, int NB)
{
    __shared__ int s[256];
    const int t = threadIdx.x;
    s[t] = (t < NB) ? bsum[t] : 0;
    __syncthreads();
    #pragma unroll
    for (int off = 1; off < 256; off <<= 1) {
        const int v = s[t];
        const int u = (t >= off) ? s[t - off] : 0;
        __syncthreads();
        s[t] = v + u;
        __syncthreads();
    }
    if (t < NB) bpre[t] = t ? s[t - 1] : 0;
}

// Block-local exclusive scan + block prefix -> offsets
__global__ __launch_bounds__(256) void scan_final(
    const int* __restrict__ counts, const int* __restrict__ bpre,
    int* __restrict__ offsets, int N)
{
    __shared__ int s[256];
    const int t = threadIdx.x;
    const int idx = blockIdx.x * 256 + t;
    const int v = (idx < N) ? counts[idx] : 0;
    s[t] = v;
    __syncthreads();
    #pragma unroll
    for (int off = 1; off < 256; off <<= 1) {
        const int a = s[t];
        const int u = (t >= off) ? s[t - off] : 0;
        __syncthreads();
        s[t] = a + u;
        __syncthreads();
    }
    if (idx < N) offsets[idx] = bpre[blockIdx.x] + s[t] - v;  // exclusive
}

// Scatter packed edge records {col, lr, li, 0} into CSR slots.
__global__ __launch_bounds__(256) void fill_csr(
    const int* __restrict__ row, const int* __restrict__ col,
    const float* __restrict__ Lr, const float* __restrict__ Li,
    const int* __restrict__ offsets, int* __restrict__ cursor,
    int4* __restrict__ meta, int E)
{
    const int e = blockIdx.x * 256 + threadIdx.x;
    if (e >= E) return;
    const int r = row[e];
    const int pos = offsets[r] + atomicAdd(cursor + r, 1);
    meta[pos] = make_int4(col[e], __float_as_int(Lr[e]), __float_as_int(Li[e]), 0);
}

// ===========================================================================
// Sort each row's edges by col (ascending). One wave per node, in-register
// bitonic sort across 64 lanes (no LDS, no barriers -- wave-synchronous).
// PURELY a locality hint: with monotone col order per row and blocks launched
// in node order, the gather performs ~11 quasi-streaming sweeps over Y
// instead of uniform-random 1KB touches -> DRAM page-hit rate up.
// deg > 64 rows are skipped (P ~ 0 for Poisson(16); correctness unaffected).
// ===========================================================================
__global__ __launch_bounds__(256) void sort_rows(
    const int* __restrict__ offsets, int4* __restrict__ meta, int N, int E)
{
    const int n = blockIdx.x * 4 + (threadIdx.x >> 6);
    if (n >= N) return;
    const int lane = threadIdx.x & 63;
    const int start = offsets[n];
    const int end   = (n + 1 < N) ? offsets[n + 1] : E;
    const int deg = end - start;
    if (deg <= 1 || deg > 64) return;   // wave-uniform; sort is perf-only

    int col, lr, li;
    if (lane < deg) {
        const int4 m = meta[start + lane];
        col = m.x; lr = m.y; li = m.z;
    } else {
        col = 0x7FFFFFFF; lr = 0; li = 0;  // sentinel sorts to tail
    }

    #pragma unroll
    for (int k = 2; k <= 64; k <<= 1) {
        #pragma unroll
        for (int j = k >> 1; j > 0; j >>= 1) {
            const int pcol = __shfl_xor(col, j);
            const int plr  = __shfl_xor(lr,  j);
            const int pli  = __shfl_xor(li,  j);
            const bool keepSmall = (((lane & j) == 0) == ((lane & k) == 0));
            const bool take = keepSmall ? (pcol < col) : (pcol > col);
            if (take) { col = pcol; lr = plr; li = pli; }
        }
    }

    if (lane < deg) meta[start + lane] = make_int4(col, lr, li, 0);
}

// ===========================================================================
// Y = [Xr;Xi] @ W, written PACKED: Y[n] = [real(128) | imag(128)] (256 floats
// per node row). Packed layout measured neutral vs split (R5) but kept: one
// 1KB block per edge synergizes with the sorted col sweep for DRAM pages.
// ===========================================================================
__global__ __launch_bounds__(256) void gemm_xw(
    const float* __restrict__ Xr, const float* __restrict__ Xi,
    const float* __restrict__ W, float* __restrict__ Y, int N)
{
    __shared__ float Ws[64 * CC];       // 32 KB (one 64-row K-chunk of W)
    __shared__ float AsT[CC][36];       // 18 KB, [k][r]
    const int t = threadIdx.x;
    const int m0 = blockIdx.x * 32;
    const int M = 2 * N;

    for (int ch = t; ch < 1024; ch += 256) {
        const int r  = ch >> 5;
        const int k0 = (ch & 31) * 4;
        const int m  = m0 + r;
        float4 q = make_float4(0.f, 0.f, 0.f, 0.f);
        if (m < M) {
            const float* src = (m < N) ? (Xr + (size_t)m * CC)
                                       : (Xi + (size_t)(m - N) * CC);
            q = *(const float4*)(src + k0);
        }
        AsT[k0 + 0][r] = q.x;
        AsT[k0 + 1][r] = q.y;
        AsT[k0 + 2][r] = q.z;
        AsT[k0 + 3][r] = q.w;
    }

    const int cg = t & 31;
    const int rs = t >> 5;
    float s[4][4];
    #pragma unroll
    for (int a = 0; a < 4; ++a)
        #pragma unroll
        for (int b = 0; b < 4; ++b) s[a][b] = 0.f;

    for (int kc = 0; kc < 2; ++kc) {
        __syncthreads();
        {
            const float4* src = (const float4*)(W + (size_t)kc * 64 * CC);
            float4* dst = (float4*)Ws;
            #pragma unroll
            for (int i = 0; i < 8; ++i) dst[t + 256 * i] = src[t + 256 * i];
        }
        __syncthreads();

        #pragma unroll 4
        for (int kk = 0; kk < 64; ++kk) {
            const int k = kc * 64 + kk;
            const float4 av = *(const float4*)&AsT[k][rs * 4];
            const float4 wv = *(const float4*)&Ws[kk * CC + cg * 4];
            const float ar[4] = {av.x, av.y, av.z, av.w};
            const float wc[4] = {wv.x, wv.y, wv.z, wv.w};
            #pragma unroll
            for (int a = 0; a < 4; ++a)
                #pragma unroll
                for (int b = 0; b < 4; ++b) s[a][b] += ar[a] * wc[b];
        }
    }

    #pragma unroll
    for (int a = 0; a < 4; ++a) {
        const int m = m0 + rs * 4 + a;
        if (m >= M) continue;
        float4 o;
        o.x = s[a][0]; o.y = s[a][1]; o.z = s[a][2]; o.w = s[a][3];
        // packed layout: node row = m % N, halves offset by 128
        float* dst = (m < N) ? (Y + (size_t)m * 256 + cg * 4)
                             : (Y + (size_t)(m - N) * 256 + 128 + cg * 4);
        *(float4*)dst = o;
    }
}

// ===========================================================================
// Fused gather: out[n] = sum_e L_e * Ypacked[col_e] + X[n]  (complex),
// 1 wave/node, 2 ch/lane, 8-edge chunks, cols sorted ascending per row.
// PLAIN __launch_bounds__(256): (256,8) caps VGPR at 32 -> compiler spills
// the pipeline to scratch (~440MB phantom WRITE, 2x dur; R1/R3/R4 signature).
// ===========================================================================
__device__ __forceinline__ void edge_acc(
    const int4 m, const float* __restrict__ Y,
    int lane, float2& aR, float2& aI)
{
    const float* base = Y + (size_t)m.x * 256 + 2 * lane;
    const float2 yr = *(const float2*)(base);
    const float2 yi = *(const float2*)(base + 128);
    const float lr = __int_as_float(m.y);
    const float li = __int_as_float(m.z);
    aR.x += lr * yr.x - li * yi.x;
    aR.y += lr * yr.y - li * yi.y;
    aI.x += li * yr.x + lr * yi.x;
    aI.y += li * yr.y + lr * yi.y;
}

__device__ __forceinline__ void cmadd(
    const int4 m, const float2 yr, const float2 yi, float2& aR, float2& aI)
{
    const float lr = __int_as_float(m.y);
    const float li = __int_as_float(m.z);
    aR.x += lr * yr.x - li * yi.x;
    aR.y += lr * yr.y - li * yi.y;
    aI.x += li * yr.x + lr * yi.x;
    aI.y += li * yr.y + lr * yi.y;
}

__global__ __launch_bounds__(256) void gather_fused(
    const float* __restrict__ Y,        // packed [N][256]
    const float* __restrict__ Xr, const float* __restrict__ Xi,
    const int* __restrict__ offsets, const int4* __restrict__ meta,
    float* __restrict__ out, int N, int E)
{
    const int n = blockIdx.x * 4 + (threadIdx.x >> 6);
    if (n >= N) return;
    const int lane = threadIdx.x & 63;
    const int start = offsets[n];
    const int end   = (n + 1 < N) ? offsets[n + 1] : E;
    const int Em1 = E - 1;

    // residual init
    float2 aR = *(const float2*)(Xr + (size_t)n * CC + 2 * lane);
    float2 aI = *(const float2*)(Xi + (size_t)n * CC + 2 * lane);

    int4 m0 = meta[min(start + 0, Em1)];
    int4 m1 = meta[min(start + 1, Em1)];
    int4 m2 = meta[min(start + 2, Em1)];
    int4 m3 = meta[min(start + 3, Em1)];
    int4 m4 = meta[min(start + 4, Em1)];
    int4 m5 = meta[min(start + 5, Em1)];
    int4 m6 = meta[min(start + 6, Em1)];
    int4 m7 = meta[min(start + 7, Em1)];

    int j = start;
    for (; j + 8 <= end; j += 8) {
        // prefetch next chunk's meta (wave-uniform)
        const int4 n0 = meta[min(j +  8, Em1)];
        const int4 n1 = meta[min(j +  9, Em1)];
        const int4 n2 = meta[min(j + 10, Em1)];
        const int4 n3 = meta[min(j + 11, Em1)];
        const int4 n4 = meta[min(j + 12, Em1)];
        const int4 n5 = meta[min(j + 13, Em1)];
        const int4 n6 = meta[min(j + 14, Em1)];
        const int4 n7 = meta[min(j + 15, Em1)];
        // 16 independent loads from 8 contiguous 1KB rows
        const float* b0 = Y + (size_t)m0.x * 256 + 2 * lane;
        const float* b1 = Y + (size_t)m1.x * 256 + 2 * lane;
        const float* b2 = Y + (size_t)m2.x * 256 + 2 * lane;
        const float* b3 = Y + (size_t)m3.x * 256 + 2 * lane;
        const float* b4 = Y + (size_t)m4.x * 256 + 2 * lane;
        const float* b5 = Y + (size_t)m5.x * 256 + 2 * lane;
        const float* b6 = Y + (size_t)m6.x * 256 + 2 * lane;
        const float* b7 = Y + (size_t)m7.x * 256 + 2 * lane;
        const float2 yr0 = *(const float2*)(b0);
        const float2 yi0 = *(const float2*)(b0 + 128);
        const float2 yr1 = *(const float2*)(b1);
        const float2 yi1 = *(const float2*)(b1 + 128);
        const float2 yr2 = *(const float2*)(b2);
        const float2 yi2 = *(const float2*)(b2 + 128);
        const float2 yr3 = *(const float2*)(b3);
        const float2 yi3 = *(const float2*)(b3 + 128);
        const float2 yr4 = *(const float2*)(b4);
        const float2 yi4 = *(const float2*)(b4 + 128);
        const float2 yr5 = *(const float2*)(b5);
        const float2 yi5 = *(const float2*)(b5 + 128);
        const float2 yr6 = *(const float2*)(b6);
        const float2 yi6 = *(const float2*)(b6 + 128);
        const float2 yr7 = *(const float2*)(b7);
        const float2 yi7 = *(const float2*)(b7 + 128);

        cmadd(m0, yr0, yi0, aR, aI);
        cmadd(m1, yr1, yi1, aR, aI);
        cmadd(m2, yr2, yi2, aR, aI);
        cmadd(m3, yr3, yi3, aR, aI);
        cmadd(m4, yr4, yi4, aR, aI);
        cmadd(m5, yr5, yi5, aR, aI);
        cmadd(m6, yr6, yi6, aR, aI);
        cmadd(m7, yr7, yi7, aR, aI);

        m0 = n0; m1 = n1; m2 = n2; m3 = n3;
        m4 = n4; m5 = n5; m6 = n6; m7 = n7;
    }
    const int r = end - j;   // 0..7 remaining edges, meta already in m0..m6
    if (r > 0) edge_acc(m0, Y, lane, aR, aI);
    if (r > 1) edge_acc(m1, Y, lane, aR, aI);
    if (r > 2) edge_acc(m2, Y, lane, aR, aI);
    if (r > 3) edge_acc(m3, Y, lane, aR, aI);
    if (r > 4) edge_acc(m4, Y, lane, aR, aI);
    if (r > 5) edge_acc(m5, Y, lane, aR, aI);
    if (r > 6) edge_acc(m6, Y, lane, aR, aI);

    *(float2*)(out + (size_t)n * CC + 2 * lane) = aR;
    *(float2*)(out + ((size_t)n + N) * CC + 2 * lane) = aI;
}

// ===========================================================================
// Fallback kernels (unchanged, proven)
// ===========================================================================
__global__ __launch_bounds__(256) void gather_nodes(
    const float* __restrict__ Xr, const float* __restrict__ Xi,
    const int* __restrict__ offsets, const int4* __restrict__ meta,
    float* __restrict__ out, int N, int E)
{
    const int n = blockIdx.x * 4 + (threadIdx.x >> 6);
    if (n >= N) return;
    const int lane = threadIdx.x & 63;
    const int start = offsets[n];
    const int end   = (n + 1 < N) ? offsets[n + 1] : E;
    float2 aR = make_float2(0.f, 0.f);
    float2 aI = make_float2(0.f, 0.f);
    for (int j = start; j < end; ++j) {
        const int4 m0 = meta[j];
        const float2 xr0 = *(const float2*)(Xr + (size_t)m0.x * CC + 2 * lane);
        const float2 xi0 = *(const float2*)(Xi + (size_t)m0.x * CC + 2 * lane);
        const float lr0 = __int_as_float(m0.y), li0 = __int_as_float(m0.z);
        aR.x += lr0 * xr0.x - li0 * xi0.x;
        aR.y += lr0 * xr0.y - li0 * xi0.y;
        aI.x += li0 * xr0.x + lr0 * xi0.x;
        aI.y += li0 * xr0.y + lr0 * xi0.y;
    }
    *(float2*)(out + (size_t)n * CC + 2 * lane) = aR;
    *(float2*)(out + ((size_t)n + N) * CC + 2 * lane) = aI;
}

__global__ __launch_bounds__(256) void scatter_edges(
    const float* __restrict__ Xr, const float* __restrict__ Xi,
    const float* __restrict__ Lr, const float* __restrict__ Li,
    const int* __restrict__ row, const int* __restrict__ col,
    float* __restrict__ out, int N, int E)
{
    const int e = blockIdx.x * 4 + (threadIdx.x >> 6);
    if (e >= E) return;
    const int lane = threadIdx.x & 63;
    const int r = row[e], c = col[e];
    const float lr = Lr[e];
    const float li = Li[e];
    const float2 xr = *(const float2*)(Xr + (size_t)c * CC + 2 * lane);
    const float2 xi = *(const float2*)(Xi + (size_t)c * CC + 2 * lane);
    float* pr = out + (size_t)r * CC + 2 * lane;
    float* pi = out + ((size_t)r + N) * CC + 2 * lane;
    unsafeAtomicAdd(pr,     lr * xr.x - li * xi.x);
    unsafeAtomicAdd(pr + 1, lr * xr.y - li * xi.y);
    unsafeAtomicAdd(pi,     li * xr.x + lr * xi.x);
    unsafeAtomicAdd(pi + 1, li * xr.y + lr * xi.y);
}

__global__ __launch_bounds__(256) void gemm_inplace(
    float* __restrict__ io, const float* __restrict__ W,
    const float* __restrict__ Xp, int N)
{
    __shared__ float Ws[64 * CC];
    __shared__ float AsT[CC][36];
    const int t = threadIdx.x;
    const int m0 = blockIdx.x * 32;

    for (int ch = t; ch < 1024; ch += 256) {
        const int r  = ch >> 5;
        const int k0 = (ch & 31) * 4;
        const int m  = m0 + r;
        float4 q = make_float4(0.f, 0.f, 0.f, 0.f);
        if (m < N) q = *(const float4*)(io + (size_t)m * CC + k0);
        AsT[k0 + 0][r] = q.x;
        AsT[k0 + 1][r] = q.y;
        AsT[k0 + 2][r] = q.z;
        AsT[k0 + 3][r] = q.w;
    }

    const int cg = t & 31;
    const int rs = t >> 5;
    float s[4][4];
    #pragma unroll
    for (int a = 0; a < 4; ++a)
        #pragma unroll
        for (int b = 0; b < 4; ++b) s[a][b] = 0.f;

    for (int kc = 0; kc < 2; ++kc) {
        __syncthreads();
        {
            const float4* src = (const float4*)(W + (size_t)kc * 64 * CC);
            float4* dst = (float4*)Ws;
            #pragma unroll
            for (int i = 0; i < 8; ++i) dst[t + 256 * i] = src[t + 256 * i];
        }
        __syncthreads();
        #pragma unroll 4
        for (int kk = 0; kk < 64; ++kk) {
            const int k = kc * 64 + kk;
            const float4 av = *(const float4*)&AsT[k][rs * 4];
            const float4 wv = *(const float4*)&Ws[kk * CC + cg * 4];
            const float ar[4] = {av.x, av.y, av.z, av.w};
            const float wc[4] = {wv.x, wv.y, wv.z, wv.w};
            #pragma unroll
            for (int a = 0; a < 4; ++a)
                #pragma unroll
                for (int b = 0; b < 4; ++b) s[a][b] += ar[a] * wc[b];
        }
    }

    #pragma unroll
    for (int a = 0; a < 4; ++a) {
        const int m = m0 + rs * 4 + a;
        if (m >= N) continue;
        const float4 xv = *(const float4*)(Xp + (size_t)m * CC + cg * 4);
        float4 o;
        o.x = s[a][0] + xv.x;
        o.y = s[a][1] + xv.y;
        o.z = s[a][2] + xv.z;
        o.w = s[a][3] + xv.w;
        *(float4*)(io + (size_t)m * CC + cg * 4) = o;
    }
}

// ===========================================================================
extern "C" void kernel_launch(void* const* d_in, const int* in_sizes, int n_in,
                              void* d_out, int out_size, void* d_ws, size_t ws_size,
                              hipStream_t stream)
{
    const float* Xr = (const float*)d_in[0];
    const float* Xi = (const float*)d_in[1];
    const float* Lr = (const float*)d_in[2];
    const float* Li = (const float*)d_in[3];
    const float* W  = (const float*)d_in[4];
    const int* row = (const int*)d_in[5];
    const int* col = (const int*)d_in[6];
    float* out = (float*)d_out;

    const int N = in_sizes[0] / CC;     // 50000
    const int E = in_sizes[2];          // 800000
    const int NB = (N + 255) / 256;     // scan blocks (196 <= 256)

    const size_t y_bytes    = (size_t)2 * N * CC * sizeof(float);  // packed [N][256]
    const size_t meta_bytes = (size_t)E * 16;
    const size_t int_bytes  = ((size_t)3 * N + 512) * sizeof(int);
    const size_t need_csr   = meta_bytes + int_bytes;
    const size_t need_fused = y_bytes + need_csr;

    if (ws_size >= need_fused) {
        float* Y      = (float*)d_ws;
        int4*  meta   = (int4*)((char*)d_ws + y_bytes);
        int*   counts = (int*)((char*)d_ws + y_bytes + meta_bytes);
        int*   cursor  = counts + N;
        int*   offsets = cursor + N;
        int*   bsum    = offsets + N;
        int*   bpre    = bsum + 256;

        hipMemsetAsync(counts, 0, (size_t)2 * N * sizeof(int), stream);
        hist_rows<<<dim3((E + 255) / 256), dim3(256), 0, stream>>>(row, counts, E);
        scan_block_reduce<<<dim3(NB), dim3(256), 0, stream>>>(counts, bsum, N);
        scan_bsum<<<dim3(1), dim3(256), 0, stream>>>(bsum, bpre, NB);
        scan_final<<<dim3(NB), dim3(256), 0, stream>>>(counts, bpre, offsets, N);
        fill_csr<<<dim3((E + 255) / 256), dim3(256), 0, stream>>>(
            row, col, Lr, Li, offsets, cursor, meta, E);
        sort_rows<<<dim3((N + 3) / 4), dim3(256), 0, stream>>>(offsets, meta, N, E);
        gemm_xw<<<dim3((2 * N + 31) / 32), dim3(256), 0, stream>>>(Xr, Xi, W, Y, N);
        gather_fused<<<dim3((N + 3) / 4), dim3(256), 0, stream>>>(
            Y, Xr, Xi, offsets, meta, out, N, E);
    } else if (ws_size >= need_csr) {
        int4* meta    = (int4*)d_ws;
        int*  counts  = (int*)((char*)d_ws + meta_bytes);
        int*  cursor  = counts + N;
        int*  offsets = cursor + N;
        int*  bsum    = offsets + N;
        int*  bpre    = bsum + 256;

        hipMemsetAsync(counts, 0, (size_t)2 * N * sizeof(int), stream);
        hist_rows<<<dim3((E + 255) / 256), dim3(256), 0, stream>>>(row, counts, E);
        scan_block_reduce<<<dim3(NB), dim3(256), 0, stream>>>(counts, bsum, N);
        scan_bsum<<<dim3(1), dim3(256), 0, stream>>>(bsum, bpre, NB);
        scan_final<<<dim3(NB), dim3(256), 0, stream>>>(counts, bpre, offsets, N);
        fill_csr<<<dim3((E + 255) / 256), dim3(256), 0, stream>>>(
            row, col, Lr, Li, offsets, cursor, meta, E);
        gather_nodes<<<dim3((N + 3) / 4), dim3(256), 0, stream>>>(
            Xr, Xi, offsets, meta, out, N, E);
        gemm_inplace<<<dim3((N + 31) / 32), dim3(256), 0, stream>>>(out, W, Xr, N);
        gemm_inplace<<<dim3((N + 31) / 32), dim3(256), 0, stream>>>(
            out + (size_t)N * CC, W, Xi, N);
    } else {
        hipMemsetAsync(out, 0, (size_t)2 * N * CC * sizeof(float), stream);
        scatter_edges<<<dim3((E + 3) / 4), dim3(256), 0, stream>>>(
            Xr, Xi, Lr, Li, row, col, out, N, E);
        gemm_inplace<<<dim3((N + 31) / 32), dim3(256), 0, stream>>>(out, W, Xr, N);
        gemm_inplace<<<dim3((N + 31) / 32), dim3(256), 0, stream>>>(
            out + (size_t)N * CC, W, Xi, N);
    }
}

// Round 7
// 312.452 us; speedup vs baseline: 1.2620x; 1.2620x over previous
//
#include <hip/hip_runtime.h>
#include <cstddef>

#define CC 128  // channels

// ===========================================================================
// CSR build: histogram -> 3-kernel parallel scan -> fill
// ===========================================================================

__global__ __launch_bounds__(256) void hist_rows(
    const int* __restrict__ row, int* __restrict__ counts, int E)
{
    const int e = blockIdx.x * 256 + threadIdx.x;
    if (e < E) atomicAdd(counts + row[e], 1);
}

// Per-block sum of 256 counts -> bsum[block]
__global__ __launch_bounds__(256) void scan_block_reduce(
    const int* __restrict__ counts, int* __restrict__ bsum, int N)
{
    __shared__ int s[256];
    const int t = threadIdx.x;
    const int idx = blockIdx.x * 256 + t;
    s[t] = (idx < N) ? counts[idx] : 0;
    __syncthreads();
    #pragma unroll
    for (int off = 128; off > 0; off >>= 1) {
        if (t < off) s[t] += s[t + off];
        __syncthreads();
    }
    if (t == 0) bsum[blockIdx.x] = s[0];
}

// Exclusive scan of NB (<=256) block sums, single block.
__global__ __launch_bounds__(256) void scan_bsum(
    const int* __restrict__ bsum, int* __restrict__ bpre, int NB)
{
    __shared__ int s[256];
    const int t = threadIdx.x;
    s[t] = (t < NB) ? bsum[t] : 0;
    __syncthreads();
    #pragma unroll
    for (int off = 1; off < 256; off <<= 1) {
        const int v = s[t];
        const int u = (t >= off) ? s[t - off] : 0;
        __syncthreads();
        s[t] = v + u;
        __syncthreads();
    }
    if (t < NB) bpre[t] = t ? s[t - 1] : 0;
}

// Block-local exclusive scan + block prefix -> offsets
__global__ __launch_bounds__(256) void scan_final(
    const int* __restrict__ counts, const int* __restrict__ bpre,
    int* __restrict__ offsets, int N)
{
    __shared__ int s[256];
    const int t = threadIdx.x;
    const int idx = blockIdx.x * 256 + t;
    const int v = (idx < N) ? counts[idx] : 0;
    s[t] = v;
    __syncthreads();
    #pragma unroll
    for (int off = 1; off < 256; off <<= 1) {
        const int a = s[t];
        const int u = (t >= off) ? s[t - off] : 0;
        __syncthreads();
        s[t] = a + u;
        __syncthreads();
    }
    if (idx < N) offsets[idx] = bpre[blockIdx.x] + s[t] - v;  // exclusive
}

// Scatter packed edge records {col, lr, li, 0} into CSR slots.
__global__ __launch_bounds__(256) void fill_csr(
    const int* __restrict__ row, const int* __restrict__ col,
    const float* __restrict__ Lr, const float* __restrict__ Li,
    const int* __restrict__ offsets, int* __restrict__ cursor,
    int4* __restrict__ meta, int E)
{
    const int e = blockIdx.x * 256 + threadIdx.x;
    if (e >= E) return;
    const int r = row[e];
    const int pos = offsets[r] + atomicAdd(cursor + r, 1);
    meta[pos] = make_int4(col[e], __float_as_int(Lr[e]), __float_as_int(Li[e]), 0);
}

// fp32 -> bf16 (round-to-nearest-even on the bit pattern)
__device__ __forceinline__ unsigned short f2bf(float f)
{
    unsigned int u = __float_as_uint(f);
    u = (u + 0x7fffu + ((u >> 16) & 1u)) >> 16;
    return (unsigned short)u;
}

// ===========================================================================
// Y = [Xr;Xi] @ W, stored PACKED bf16: Y[n] = [real(128)|imag(128)] bf16
// (512 B per node row). The gather is byte-bound on the L2-miss/fabric path
// (R6: address order neutral at equal bytes) -> halving Y bytes is the lever.
// Accumulation stays fp32 everywhere; only Y storage is bf16 (RNE).
// ===========================================================================
__global__ __launch_bounds__(256) void gemm_xw(
    const float* __restrict__ Xr, const float* __restrict__ Xi,
    const float* __restrict__ W, unsigned short* __restrict__ Y, int N)
{
    __shared__ float Ws[64 * CC];       // 32 KB (one 64-row K-chunk of W)
    __shared__ float AsT[CC][36];       // 18 KB, [k][r]
    const int t = threadIdx.x;
    const int m0 = blockIdx.x * 32;
    const int M = 2 * N;

    for (int ch = t; ch < 1024; ch += 256) {
        const int r  = ch >> 5;
        const int k0 = (ch & 31) * 4;
        const int m  = m0 + r;
        float4 q = make_float4(0.f, 0.f, 0.f, 0.f);
        if (m < M) {
            const float* src = (m < N) ? (Xr + (size_t)m * CC)
                                       : (Xi + (size_t)(m - N) * CC);
            q = *(const float4*)(src + k0);
        }
        AsT[k0 + 0][r] = q.x;
        AsT[k0 + 1][r] = q.y;
        AsT[k0 + 2][r] = q.z;
        AsT[k0 + 3][r] = q.w;
    }

    const int cg = t & 31;
    const int rs = t >> 5;
    float s[4][4];
    #pragma unroll
    for (int a = 0; a < 4; ++a)
        #pragma unroll
        for (int b = 0; b < 4; ++b) s[a][b] = 0.f;

    for (int kc = 0; kc < 2; ++kc) {
        __syncthreads();
        {
            const float4* src = (const float4*)(W + (size_t)kc * 64 * CC);
            float4* dst = (float4*)Ws;
            #pragma unroll
            for (int i = 0; i < 8; ++i) dst[t + 256 * i] = src[t + 256 * i];
        }
        __syncthreads();

        #pragma unroll 4
        for (int kk = 0; kk < 64; ++kk) {
            const int k = kc * 64 + kk;
            const float4 av = *(const float4*)&AsT[k][rs * 4];
            const float4 wv = *(const float4*)&Ws[kk * CC + cg * 4];
            const float ar[4] = {av.x, av.y, av.z, av.w};
            const float wc[4] = {wv.x, wv.y, wv.z, wv.w};
            #pragma unroll
            for (int a = 0; a < 4; ++a)
                #pragma unroll
                for (int b = 0; b < 4; ++b) s[a][b] += ar[a] * wc[b];
        }
    }

    #pragma unroll
    for (int a = 0; a < 4; ++a) {
        const int m = m0 + rs * 4 + a;
        if (m >= M) continue;
        ushort4 o;
        o.x = f2bf(s[a][0]); o.y = f2bf(s[a][1]);
        o.z = f2bf(s[a][2]); o.w = f2bf(s[a][3]);
        // packed layout: node row = m % N, halves offset by 128 bf16
        unsigned short* dst = (m < N)
            ? (Y + (size_t)m * 256 + cg * 4)
            : (Y + (size_t)(m - N) * 256 + 128 + cg * 4);
        *(ushort4*)dst = o;   // 8B coalesced store
    }
}

// ===========================================================================
// Fused gather: out[n] = sum_e L_e * Ybf16[col_e] + X[n]  (complex),
// 1 wave/node, 2 ch/lane, 8-edge chunks. Each edge reads 512B contiguous
// (2x uint per lane, real half + imag half). bf16->fp32 = 2 bitops/dword.
// PLAIN __launch_bounds__(256): (256,8) caps VGPR at 32 -> spill-to-scratch
// disaster (~440MB phantom WRITE, R1/R3/R4 signature).
// ===========================================================================
__device__ __forceinline__ void cmadd_bf(
    const int4 m, const unsigned int ur, const unsigned int ui,
    float2& aR, float2& aI)
{
    const float lr = __int_as_float(m.y);
    const float li = __int_as_float(m.z);
    const float yrx = __uint_as_float(ur << 16);
    const float yry = __uint_as_float(ur & 0xFFFF0000u);
    const float yix = __uint_as_float(ui << 16);
    const float yiy = __uint_as_float(ui & 0xFFFF0000u);
    aR.x += lr * yrx - li * yix;
    aR.y += lr * yry - li * yiy;
    aI.x += li * yrx + lr * yix;
    aI.y += li * yry + lr * yiy;
}

__device__ __forceinline__ void edge_acc(
    const int4 m, const unsigned short* __restrict__ Y,
    int lane, float2& aR, float2& aI)
{
    const unsigned short* b = Y + (size_t)m.x * 256 + 2 * lane;
    const unsigned int ur = *(const unsigned int*)(b);
    const unsigned int ui = *(const unsigned int*)(b + 128);
    cmadd_bf(m, ur, ui, aR, aI);
}

__global__ __launch_bounds__(256) void gather_fused(
    const unsigned short* __restrict__ Y,  // packed bf16 [N][256]
    const float* __restrict__ Xr, const float* __restrict__ Xi,
    const int* __restrict__ offsets, const int4* __restrict__ meta,
    float* __restrict__ out, int N, int E)
{
    const int n = blockIdx.x * 4 + (threadIdx.x >> 6);
    if (n >= N) return;
    const int lane = threadIdx.x & 63;
    const int start = offsets[n];
    const int end   = (n + 1 < N) ? offsets[n + 1] : E;
    const int Em1 = E - 1;

    // residual init
    float2 aR = *(const float2*)(Xr + (size_t)n * CC + 2 * lane);
    float2 aI = *(const float2*)(Xi + (size_t)n * CC + 2 * lane);

    int4 m0 = meta[min(start + 0, Em1)];
    int4 m1 = meta[min(start + 1, Em1)];
    int4 m2 = meta[min(start + 2, Em1)];
    int4 m3 = meta[min(start + 3, Em1)];
    int4 m4 = meta[min(start + 4, Em1)];
    int4 m5 = meta[min(start + 5, Em1)];
    int4 m6 = meta[min(start + 6, Em1)];
    int4 m7 = meta[min(start + 7, Em1)];

    int j = start;
    for (; j + 8 <= end; j += 8) {
        // prefetch next chunk's meta (wave-uniform)
        const int4 n0 = meta[min(j +  8, Em1)];
        const int4 n1 = meta[min(j +  9, Em1)];
        const int4 n2 = meta[min(j + 10, Em1)];
        const int4 n3 = meta[min(j + 11, Em1)];
        const int4 n4 = meta[min(j + 12, Em1)];
        const int4 n5 = meta[min(j + 13, Em1)];
        const int4 n6 = meta[min(j + 14, Em1)];
        const int4 n7 = meta[min(j + 15, Em1)];
        // 16 independent dword loads from 8 contiguous 512B rows
        const unsigned short* b0 = Y + (size_t)m0.x * 256 + 2 * lane;
        const unsigned short* b1 = Y + (size_t)m1.x * 256 + 2 * lane;
        const unsigned short* b2 = Y + (size_t)m2.x * 256 + 2 * lane;
        const unsigned short* b3 = Y + (size_t)m3.x * 256 + 2 * lane;
        const unsigned short* b4 = Y + (size_t)m4.x * 256 + 2 * lane;
        const unsigned short* b5 = Y + (size_t)m5.x * 256 + 2 * lane;
        const unsigned short* b6 = Y + (size_t)m6.x * 256 + 2 * lane;
        const unsigned short* b7 = Y + (size_t)m7.x * 256 + 2 * lane;
        const unsigned int ur0 = *(const unsigned int*)(b0);
        const unsigned int ui0 = *(const unsigned int*)(b0 + 128);
        const unsigned int ur1 = *(const unsigned int*)(b1);
        const unsigned int ui1 = *(const unsigned int*)(b1 + 128);
        const unsigned int ur2 = *(const unsigned int*)(b2);
        const unsigned int ui2 = *(const unsigned int*)(b2 + 128);
        const unsigned int ur3 = *(const unsigned int*)(b3);
        const unsigned int ui3 = *(const unsigned int*)(b3 + 128);
        const unsigned int ur4 = *(const unsigned int*)(b4);
        const unsigned int ui4 = *(const unsigned int*)(b4 + 128);
        const unsigned int ur5 = *(const unsigned int*)(b5);
        const unsigned int ui5 = *(const unsigned int*)(b5 + 128);
        const unsigned int ur6 = *(const unsigned int*)(b6);
        const unsigned int ui6 = *(const unsigned int*)(b6 + 128);
        const unsigned int ur7 = *(const unsigned int*)(b7);
        const unsigned int ui7 = *(const unsigned int*)(b7 + 128);

        cmadd_bf(m0, ur0, ui0, aR, aI);
        cmadd_bf(m1, ur1, ui1, aR, aI);
        cmadd_bf(m2, ur2, ui2, aR, aI);
        cmadd_bf(m3, ur3, ui3, aR, aI);
        cmadd_bf(m4, ur4, ui4, aR, aI);
        cmadd_bf(m5, ur5, ui5, aR, aI);
        cmadd_bf(m6, ur6, ui6, aR, aI);
        cmadd_bf(m7, ur7, ui7, aR, aI);

        m0 = n0; m1 = n1; m2 = n2; m3 = n3;
        m4 = n4; m5 = n5; m6 = n6; m7 = n7;
    }
    const int r = end - j;   // 0..7 remaining edges, meta already in m0..m6
    if (r > 0) edge_acc(m0, Y, lane, aR, aI);
    if (r > 1) edge_acc(m1, Y, lane, aR, aI);
    if (r > 2) edge_acc(m2, Y, lane, aR, aI);
    if (r > 3) edge_acc(m3, Y, lane, aR, aI);
    if (r > 4) edge_acc(m4, Y, lane, aR, aI);
    if (r > 5) edge_acc(m5, Y, lane, aR, aI);
    if (r > 6) edge_acc(m6, Y, lane, aR, aI);

    *(float2*)(out + (size_t)n * CC + 2 * lane) = aR;
    *(float2*)(out + ((size_t)n + N) * CC + 2 * lane) = aI;
}

// ===========================================================================
// Fallback kernels (unchanged, proven, full fp32)
// ===========================================================================
__global__ __launch_bounds__(256) void gather_nodes(
    const float* __restrict__ Xr, const float* __restrict__ Xi,
    const int* __restrict__ offsets, const int4* __restrict__ meta,
    float* __restrict__ out, int N, int E)
{
    const int n = blockIdx.x * 4 + (threadIdx.x >> 6);
    if (n >= N) return;
    const int lane = threadIdx.x & 63;
    const int start = offsets[n];
    const int end   = (n + 1 < N) ? offsets[n + 1] : E;
    float2 aR = make_float2(0.f, 0.f);
    float2 aI = make_float2(0.f, 0.f);
    for (int j = start; j < end; ++j) {
        const int4 m0 = meta[j];
        const float2 xr0 = *(const float2*)(Xr + (size_t)m0.x * CC + 2 * lane);
        const float2 xi0 = *(const float2*)(Xi + (size_t)m0.x * CC + 2 * lane);
        const float lr0 = __int_as_float(m0.y), li0 = __int_as_float(m0.z);
        aR.x += lr0 * xr0.x - li0 * xi0.x;
        aR.y += lr0 * xr0.y - li0 * xi0.y;
        aI.x += li0 * xr0.x + lr0 * xi0.x;
        aI.y += li0 * xr0.y + lr0 * xi0.y;
    }
    *(float2*)(out + (size_t)n * CC + 2 * lane) = aR;
    *(float2*)(out + ((size_t)n + N) * CC + 2 * lane) = aI;
}

__global__ __launch_bounds__(256) void scatter_edges(
    const float* __restrict__ Xr, const float* __restrict__ Xi,
    const float* __restrict__ Lr, const float* __restrict__ Li,
    const int* __restrict__ row, const int* __restrict__ col,
    float* __restrict__ out, int N, int E)
{
    const int e = blockIdx.x * 4 + (threadIdx.x >> 6);
    if (e >= E) return;
    const int lane = threadIdx.x & 63;
    const int r = row[e], c = col[e];
    const float lr = Lr[e];
    const float li = Li[e];
    const float2 xr = *(const float2*)(Xr + (size_t)c * CC + 2 * lane);
    const float2 xi = *(const float2*)(Xi + (size_t)c * CC + 2 * lane);
    float* pr = out + (size_t)r * CC + 2 * lane;
    float* pi = out + ((size_t)r + N) * CC + 2 * lane;
    unsafeAtomicAdd(pr,     lr * xr.x - li * xi.x);
    unsafeAtomicAdd(pr + 1, lr * xr.y - li * xi.y);
    unsafeAtomicAdd(pi,     li * xr.x + lr * xi.x);
    unsafeAtomicAdd(pi + 1, li * xr.y + lr * xi.y);
}

__global__ __launch_bounds__(256) void gemm_inplace(
    float* __restrict__ io, const float* __restrict__ W,
    const float* __restrict__ Xp, int N)
{
    __shared__ float Ws[64 * CC];
    __shared__ float AsT[CC][36];
    const int t = threadIdx.x;
    const int m0 = blockIdx.x * 32;

    for (int ch = t; ch < 1024; ch += 256) {
        const int r  = ch >> 5;
        const int k0 = (ch & 31) * 4;
        const int m  = m0 + r;
        float4 q = make_float4(0.f, 0.f, 0.f, 0.f);
        if (m < N) q = *(const float4*)(io + (size_t)m * CC + k0);
        AsT[k0 + 0][r] = q.x;
        AsT[k0 + 1][r] = q.y;
        AsT[k0 + 2][r] = q.z;
        AsT[k0 + 3][r] = q.w;
    }

    const int cg = t & 31;
    const int rs = t >> 5;
    float s[4][4];
    #pragma unroll
    for (int a = 0; a < 4; ++a)
        #pragma unroll
        for (int b = 0; b < 4; ++b) s[a][b] = 0.f;

    for (int kc = 0; kc < 2; ++kc) {
        __syncthreads();
        {
            const float4* src = (const float4*)(W + (size_t)kc * 64 * CC);
            float4* dst = (float4*)Ws;
            #pragma unroll
            for (int i = 0; i < 8; ++i) dst[t + 256 * i] = src[t + 256 * i];
        }
        __syncthreads();
        #pragma unroll 4
        for (int kk = 0; kk < 64; ++kk) {
            const int k = kc * 64 + kk;
            const float4 av = *(const float4*)&AsT[k][rs * 4];
            const float4 wv = *(const float4*)&Ws[kk * CC + cg * 4];
            const float ar[4] = {av.x, av.y, av.z, av.w};
            const float wc[4] = {wv.x, wv.y, wv.z, wv.w};
            #pragma unroll
            for (int a = 0; a < 4; ++a)
                #pragma unroll
                for (int b = 0; b < 4; ++b) s[a][b] += ar[a] * wc[b];
        }
    }

    #pragma unroll
    for (int a = 0; a < 4; ++a) {
        const int m = m0 + rs * 4 + a;
        if (m >= N) continue;
        const float4 xv = *(const float4*)(Xp + (size_t)m * CC + cg * 4);
        float4 o;
        o.x = s[a][0] + xv.x;
        o.y = s[a][1] + xv.y;
        o.z = s[a][2] + xv.z;
        o.w = s[a][3] + xv.w;
        *(float4*)(io + (size_t)m * CC + cg * 4) = o;
    }
}

// ===========================================================================
extern "C" void kernel_launch(void* const* d_in, const int* in_sizes, int n_in,
                              void* d_out, int out_size, void* d_ws, size_t ws_size,
                              hipStream_t stream)
{
    const float* Xr = (const float*)d_in[0];
    const float* Xi = (const float*)d_in[1];
    const float* Lr = (const float*)d_in[2];
    const float* Li = (const float*)d_in[3];
    const float* W  = (const float*)d_in[4];
    const int* row = (const int*)d_in[5];
    const int* col = (const int*)d_in[6];
    float* out = (float*)d_out;

    const int N = in_sizes[0] / CC;     // 50000
    const int E = in_sizes[2];          // 800000
    const int NB = (N + 255) / 256;     // scan blocks (196 <= 256)

    const size_t y_bytes    = (size_t)N * 256 * sizeof(unsigned short); // bf16 packed
    const size_t meta_bytes = (size_t)E * 16;
    const size_t int_bytes  = ((size_t)3 * N + 512) * sizeof(int);
    const size_t need_csr   = meta_bytes + int_bytes;
    const size_t need_fused = y_bytes + need_csr;

    if (ws_size >= need_fused) {
        unsigned short* Y = (unsigned short*)d_ws;
        int4*  meta   = (int4*)((char*)d_ws + y_bytes);
        int*   counts = (int*)((char*)d_ws + y_bytes + meta_bytes);
        int*   cursor  = counts + N;
        int*   offsets = cursor + N;
        int*   bsum    = offsets + N;
        int*   bpre    = bsum + 256;

        hipMemsetAsync(counts, 0, (size_t)2 * N * sizeof(int), stream);
        hist_rows<<<dim3((E + 255) / 256), dim3(256), 0, stream>>>(row, counts, E);
        scan_block_reduce<<<dim3(NB), dim3(256), 0, stream>>>(counts, bsum, N);
        scan_bsum<<<dim3(1), dim3(256), 0, stream>>>(bsum, bpre, NB);
        scan_final<<<dim3(NB), dim3(256), 0, stream>>>(counts, bpre, offsets, N);
        fill_csr<<<dim3((E + 255) / 256), dim3(256), 0, stream>>>(
            row, col, Lr, Li, offsets, cursor, meta, E);
        gemm_xw<<<dim3((2 * N + 31) / 32), dim3(256), 0, stream>>>(Xr, Xi, W, Y, N);
        gather_fused<<<dim3((N + 3) / 4), dim3(256), 0, stream>>>(
            Y, Xr, Xi, offsets, meta, out, N, E);
    } else if (ws_size >= need_csr) {
        int4* meta    = (int4*)d_ws;
        int*  counts  = (int*)((char*)d_ws + meta_bytes);
        int*  cursor  = counts + N;
        int*  offsets = cursor + N;
        int*  bsum    = offsets + N;
        int*  bpre    = bsum + 256;

        hipMemsetAsync(counts, 0, (size_t)2 * N * sizeof(int), stream);
        hist_rows<<<dim3((E + 255) / 256), dim3(256), 0, stream>>>(row, counts, E);
        scan_block_reduce<<<dim3(NB), dim3(256), 0, stream>>>(counts, bsum, N);
        scan_bsum<<<dim3(1), dim3(256), 0, stream>>>(bsum, bpre, NB);
        scan_final<<<dim3(NB), dim3(256), 0, stream>>>(counts, bpre, offsets, N);
        fill_csr<<<dim3((E + 255) / 256), dim3(256), 0, stream>>>(
            row, col, Lr, Li, offsets, cursor, meta, E);
        gather_nodes<<<dim3((N + 3) / 4), dim3(256), 0, stream>>>(
            Xr, Xi, offsets, meta, out, N, E);
        gemm_inplace<<<dim3((N + 31) / 32), dim3(256), 0, stream>>>(out, W, Xr, N);
        gemm_inplace<<<dim3((N + 31) / 32), dim3(256), 0, stream>>>(
            out + (size_t)N * CC, W, Xi, N);
    } else {
        hipMemsetAsync(out, 0, (size_t)2 * N * CC * sizeof(float), stream);
        scatter_edges<<<dim3((E + 3) / 4), dim3(256), 0, stream>>>(
            Xr, Xi, Lr, Li, row, col, out, N, E);
        gemm_inplace<<<dim3((N + 31) / 32), dim3(256), 0, stream>>>(out, W, Xr, N);
        gemm_inplace<<<dim3((N + 31) / 32), dim3(256), 0, stream>>>(
            out + (size_t)N * CC, W, Xi, N);
    }
}

// Round 8
// 280.850 us; speedup vs baseline: 1.4040x; 1.1125x over previous
//
#include <hip/hip_runtime.h>
#include <cstddef>

#define CC 128  // channels

typedef __attribute__((ext_vector_type(8))) short bf16x8;
typedef __attribute__((ext_vector_type(4))) float f32x4;

// ===========================================================================
// CSR build: histogram -> 3-kernel parallel scan -> fill
// ===========================================================================

__global__ __launch_bounds__(256) void hist_rows(
    const int* __restrict__ row, int* __restrict__ counts, int E)
{
    const int e = blockIdx.x * 256 + threadIdx.x;
    if (e < E) atomicAdd(counts + row[e], 1);
}

// Per-block sum of 256 counts -> bsum[block]
__global__ __launch_bounds__(256) void scan_block_reduce(
    const int* __restrict__ counts, int* __restrict__ bsum, int N)
{
    __shared__ int s[256];
    const int t = threadIdx.x;
    const int idx = blockIdx.x * 256 + t;
    s[t] = (idx < N) ? counts[idx] : 0;
    __syncthreads();
    #pragma unroll
    for (int off = 128; off > 0; off >>= 1) {
        if (t < off) s[t] += s[t + off];
        __syncthreads();
    }
    if (t == 0) bsum[blockIdx.x] = s[0];
}

// Exclusive scan of NB (<=256) block sums, single block.
__global__ __launch_bounds__(256) void scan_bsum(
    const int* __restrict__ bsum, int* __restrict__ bpre, int NB)
{
    __shared__ int s[256];
    const int t = threadIdx.x;
    s[t] = (t < NB) ? bsum[t] : 0;
    __syncthreads();
    #pragma unroll
    for (int off = 1; off < 256; off <<= 1) {
        const int v = s[t];
        const int u = (t >= off) ? s[t - off] : 0;
        __syncthreads();
        s[t] = v + u;
        __syncthreads();
    }
    if (t < NB) bpre[t] = t ? s[t - 1] : 0;
}

// Block-local exclusive scan + block prefix -> offsets
__global__ __launch_bounds__(256) void scan_final(
    const int* __restrict__ counts, const int* __restrict__ bpre,
    int* __restrict__ offsets, int N)
{
    __shared__ int s[256];
    const int t = threadIdx.x;
    const int idx = blockIdx.x * 256 + t;
    const int v = (idx < N) ? counts[idx] : 0;
    s[t] = v;
    __syncthreads();
    #pragma unroll
    for (int off = 1; off < 256; off <<= 1) {
        const int a = s[t];
        const int u = (t >= off) ? s[t - off] : 0;
        __syncthreads();
        s[t] = a + u;
        __syncthreads();
    }
    if (idx < N) offsets[idx] = bpre[blockIdx.x] + s[t] - v;  // exclusive
}

// Scatter packed edge records {col, lr, li, 0} into CSR slots.
__global__ __launch_bounds__(256) void fill_csr(
    const int* __restrict__ row, const int* __restrict__ col,
    const float* __restrict__ Lr, const float* __restrict__ Li,
    const int* __restrict__ offsets, int* __restrict__ cursor,
    int4* __restrict__ meta, int E)
{
    const int e = blockIdx.x * 256 + threadIdx.x;
    if (e >= E) return;
    const int r = row[e];
    const int pos = offsets[r] + atomicAdd(cursor + r, 1);
    meta[pos] = make_int4(col[e], __float_as_int(Lr[e]), __float_as_int(Li[e]), 0);
}

// fp32 -> bf16 (round-to-nearest-even on the bit pattern)
__device__ __forceinline__ unsigned short f2bf(float f)
{
    unsigned int u = __float_as_uint(f);
    u = (u + 0x7fffu + ((u >> 16) & 1u)) >> 16;
    return (unsigned short)u;
}

__device__ __forceinline__ unsigned int pack2(float a, float b)
{
    return (unsigned int)f2bf(a) | ((unsigned int)f2bf(b) << 16);
}

// ===========================================================================
// One-shot: Wt[n][k] = bf16(W[k][n]), PRE-SWIZZLED for LDS b128 reads:
// within each 256B row, 16B block at byte (2k) lands at byte (2k)^((n&7)<<4).
// 16K elems, trivial cost; lets the GEMM stage W with a straight b128 copy.
// ===========================================================================
__global__ __launch_bounds__(256) void conv_w(
    const float* __restrict__ W, unsigned short* __restrict__ Wt)
{
    const int idx = blockIdx.x * 256 + threadIdx.x;   // 64 blocks x 256
    if (idx >= CC * CC) return;
    const int k = idx >> 7;          // coalesced read of W[k][n]
    const int n = idx & 127;
    const unsigned int sw = ((unsigned)(2 * k) ^ (((unsigned)n & 7u) << 4)) >> 1;
    Wt[(size_t)n * 128 + sw] = f2bf(W[idx]);
}

// ===========================================================================
// Y = [Xr;Xi] @ W via bf16 MFMA (fp32 accumulate), Y packed bf16 [N][256].
// Block: 64 rows x 128 cols, K=128 entirely in LDS (one barrier, no K-tiling).
// 4 waves in 2x2 grid; each wave 32x64 out = 8 acc tiles; per K-step (32):
// 2 a-frags + 4 b-frags (ds_read_b128, XOR-swizzled rows) + 8 MFMA.
// Fragment layout (m92-verified): lane l holds 8 consecutive k at
// k=(l>>4)*8 for row/col (l&15); C/D: col=l&15, row=(l>>4)*4+reg [m89].
// ===========================================================================
__global__ __launch_bounds__(256) void gemm_xw_mfma(
    const float* __restrict__ Xr, const float* __restrict__ Xi,
    const unsigned short* __restrict__ Wt,   // pre-swizzled bf16 [128][128]
    unsigned short* __restrict__ Y, int N)
{
    __shared__ unsigned short Bs[128 * 128];   // 32 KB (Wt, swizzled rows n)
    __shared__ unsigned short As[64 * 128];    // 16 KB (A tile, swizzled rows r)
    const int t = threadIdx.x;
    const int m0 = blockIdx.x * 64;
    const int M = 2 * N;

    // stage Wt: straight 32KB copy (already swizzled)
    {
        const uint4* src = (const uint4*)Wt;
        uint4* dst = (uint4*)Bs;
        #pragma unroll
        for (int i = 0; i < 8; ++i) dst[t + 256 * i] = src[t + 256 * i];
    }
    // stage A: 1024 x 16B blocks; fp32 -> bf16 convert, swizzled write
    #pragma unroll
    for (int i = 0; i < 4; ++i) {
        const int blk = t + 256 * i;
        const int r  = blk >> 4;          // 0..63
        const int k0 = (blk & 15) * 8;    // 0..120
        const int m  = m0 + r;
        float4 q0 = make_float4(0.f, 0.f, 0.f, 0.f);
        float4 q1 = make_float4(0.f, 0.f, 0.f, 0.f);
        if (m < M) {
            const float* src = (m < N) ? (Xr + (size_t)m * CC)
                                       : (Xi + (size_t)(m - N) * CC);
            q0 = *(const float4*)(src + k0);
            q1 = *(const float4*)(src + k0 + 4);
        }
        uint4 h;
        h.x = pack2(q0.x, q0.y);
        h.y = pack2(q0.z, q0.w);
        h.z = pack2(q1.x, q1.y);
        h.w = pack2(q1.z, q1.w);
        const int byte = r * 256 + ((2 * k0) ^ ((r & 7) << 4));
        *(uint4*)((char*)As + byte) = h;
    }
    __syncthreads();

    const int w = t >> 6, lane = t & 63;
    const int wr = w >> 1, wc = w & 1;     // 2x2 wave grid
    const int r0 = wr * 32;                // local row base (32 rows/wave)
    const int c0 = wc * 64;                // local col base (64 cols/wave)
    const int lr = lane & 15;              // frag row/col index
    const int lk = lane >> 4;              // k-group (0..3)

    f32x4 acc[2][4];
    #pragma unroll
    for (int a = 0; a < 2; ++a)
        #pragma unroll
        for (int b = 0; b < 4; ++b)
            acc[a][b] = (f32x4){0.f, 0.f, 0.f, 0.f};

    #pragma unroll
    for (int kk = 0; kk < 4; ++kk) {
        const int kbase = kk * 32 + lk * 8;
        bf16x8 afrag[2];
        #pragma unroll
        for (int at = 0; at < 2; ++at) {
            const int row = r0 + at * 16 + lr;
            afrag[at] = *(const bf16x8*)((const char*)As +
                row * 256 + ((2 * kbase) ^ ((row & 7) << 4)));
        }
        #pragma unroll
        for (int bt = 0; bt < 4; ++bt) {
            const int col = c0 + bt * 16 + lr;
            const bf16x8 bfrag = *(const bf16x8*)((const char*)Bs +
                col * 256 + ((2 * kbase) ^ ((col & 7) << 4)));
            acc[0][bt] = __builtin_amdgcn_mfma_f32_16x16x32_bf16(
                afrag[0], bfrag, acc[0][bt], 0, 0, 0);
            acc[1][bt] = __builtin_amdgcn_mfma_f32_16x16x32_bf16(
                afrag[1], bfrag, acc[1][bt], 0, 0, 0);
        }
    }

    // store: C/D lane mapping col=lane&15, row=(lane>>4)*4+v
    #pragma unroll
    for (int at = 0; at < 2; ++at) {
        #pragma unroll
        for (int v = 0; v < 4; ++v) {
            const int m = m0 + r0 + at * 16 + lk * 4 + v;
            if (m >= M) continue;
            const int node = (m < N) ? m : m - N;
            const int half = (m < N) ? 0 : 128;
            unsigned short* dst = Y + (size_t)node * 256 + half;
            #pragma unroll
            for (int bt = 0; bt < 4; ++bt)
                dst[c0 + bt * 16 + lr] = f2bf(acc[at][bt][v]);
        }
    }
}

// ===========================================================================
// Fused gather: out[n] = sum_e L_e * Ybf16[col_e] + X[n]  (complex),
// 1 wave/node, 2 ch/lane, 8-edge chunks. Each edge reads 512B contiguous.
// PLAIN __launch_bounds__(256): (256,8) caps VGPR at 32 -> spill disaster.
// ===========================================================================
__device__ __forceinline__ void cmadd_bf(
    const int4 m, const unsigned int ur, const unsigned int ui,
    float2& aR, float2& aI)
{
    const float lr = __int_as_float(m.y);
    const float li = __int_as_float(m.z);
    const float yrx = __uint_as_float(ur << 16);
    const float yry = __uint_as_float(ur & 0xFFFF0000u);
    const float yix = __uint_as_float(ui << 16);
    const float yiy = __uint_as_float(ui & 0xFFFF0000u);
    aR.x += lr * yrx - li * yix;
    aR.y += lr * yry - li * yiy;
    aI.x += li * yrx + lr * yix;
    aI.y += li * yry + lr * yiy;
}

__device__ __forceinline__ void edge_acc(
    const int4 m, const unsigned short* __restrict__ Y,
    int lane, float2& aR, float2& aI)
{
    const unsigned short* b = Y + (size_t)m.x * 256 + 2 * lane;
    const unsigned int ur = *(const unsigned int*)(b);
    const unsigned int ui = *(const unsigned int*)(b + 128);
    cmadd_bf(m, ur, ui, aR, aI);
}

__global__ __launch_bounds__(256) void gather_fused(
    const unsigned short* __restrict__ Y,  // packed bf16 [N][256]
    const float* __restrict__ Xr, const float* __restrict__ Xi,
    const int* __restrict__ offsets, const int4* __restrict__ meta,
    float* __restrict__ out, int N, int E)
{
    const int n = blockIdx.x * 4 + (threadIdx.x >> 6);
    if (n >= N) return;
    const int lane = threadIdx.x & 63;
    const int start = offsets[n];
    const int end   = (n + 1 < N) ? offsets[n + 1] : E;
    const int Em1 = E - 1;

    // residual init
    float2 aR = *(const float2*)(Xr + (size_t)n * CC + 2 * lane);
    float2 aI = *(const float2*)(Xi + (size_t)n * CC + 2 * lane);

    int4 m0 = meta[min(start + 0, Em1)];
    int4 m1 = meta[min(start + 1, Em1)];
    int4 m2 = meta[min(start + 2, Em1)];
    int4 m3 = meta[min(start + 3, Em1)];
    int4 m4 = meta[min(start + 4, Em1)];
    int4 m5 = meta[min(start + 5, Em1)];
    int4 m6 = meta[min(start + 6, Em1)];
    int4 m7 = meta[min(start + 7, Em1)];

    int j = start;
    for (; j + 8 <= end; j += 8) {
        // prefetch next chunk's meta (wave-uniform)
        const int4 n0 = meta[min(j +  8, Em1)];
        const int4 n1 = meta[min(j +  9, Em1)];
        const int4 n2 = meta[min(j + 10, Em1)];
        const int4 n3 = meta[min(j + 11, Em1)];
        const int4 n4 = meta[min(j + 12, Em1)];
        const int4 n5 = meta[min(j + 13, Em1)];
        const int4 n6 = meta[min(j + 14, Em1)];
        const int4 n7 = meta[min(j + 15, Em1)];
        // 16 independent dword loads from 8 contiguous 512B rows
        const unsigned short* b0 = Y + (size_t)m0.x * 256 + 2 * lane;
        const unsigned short* b1 = Y + (size_t)m1.x * 256 + 2 * lane;
        const unsigned short* b2 = Y + (size_t)m2.x * 256 + 2 * lane;
        const unsigned short* b3 = Y + (size_t)m3.x * 256 + 2 * lane;
        const unsigned short* b4 = Y + (size_t)m4.x * 256 + 2 * lane;
        const unsigned short* b5 = Y + (size_t)m5.x * 256 + 2 * lane;
        const unsigned short* b6 = Y + (size_t)m6.x * 256 + 2 * lane;
        const unsigned short* b7 = Y + (size_t)m7.x * 256 + 2 * lane;
        const unsigned int ur0 = *(const unsigned int*)(b0);
        const unsigned int ui0 = *(const unsigned int*)(b0 + 128);
        const unsigned int ur1 = *(const unsigned int*)(b1);
        const unsigned int ui1 = *(const unsigned int*)(b1 + 128);
        const unsigned int ur2 = *(const unsigned int*)(b2);
        const unsigned int ui2 = *(const unsigned int*)(b2 + 128);
        const unsigned int ur3 = *(const unsigned int*)(b3);
        const unsigned int ui3 = *(const unsigned int*)(b3 + 128);
        const unsigned int ur4 = *(const unsigned int*)(b4);
        const unsigned int ui4 = *(const unsigned int*)(b4 + 128);
        const unsigned int ur5 = *(const unsigned int*)(b5);
        const unsigned int ui5 = *(const unsigned int*)(b5 + 128);
        const unsigned int ur6 = *(const unsigned int*)(b6);
        const unsigned int ui6 = *(const unsigned int*)(b6 + 128);
        const unsigned int ur7 = *(const unsigned int*)(b7);
        const unsigned int ui7 = *(const unsigned int*)(b7 + 128);

        cmadd_bf(m0, ur0, ui0, aR, aI);
        cmadd_bf(m1, ur1, ui1, aR, aI);
        cmadd_bf(m2, ur2, ui2, aR, aI);
        cmadd_bf(m3, ur3, ui3, aR, aI);
        cmadd_bf(m4, ur4, ui4, aR, aI);
        cmadd_bf(m5, ur5, ui5, aR, aI);
        cmadd_bf(m6, ur6, ui6, aR, aI);
        cmadd_bf(m7, ur7, ui7, aR, aI);

        m0 = n0; m1 = n1; m2 = n2; m3 = n3;
        m4 = n4; m5 = n5; m6 = n6; m7 = n7;
    }
    const int r = end - j;   // 0..7 remaining edges, meta already in m0..m6
    if (r > 0) edge_acc(m0, Y, lane, aR, aI);
    if (r > 1) edge_acc(m1, Y, lane, aR, aI);
    if (r > 2) edge_acc(m2, Y, lane, aR, aI);
    if (r > 3) edge_acc(m3, Y, lane, aR, aI);
    if (r > 4) edge_acc(m4, Y, lane, aR, aI);
    if (r > 5) edge_acc(m5, Y, lane, aR, aI);
    if (r > 6) edge_acc(m6, Y, lane, aR, aI);

    *(float2*)(out + (size_t)n * CC + 2 * lane) = aR;
    *(float2*)(out + ((size_t)n + N) * CC + 2 * lane) = aI;
}

// ===========================================================================
// Fallback kernels (unchanged, proven, full fp32)
// ===========================================================================
__global__ __launch_bounds__(256) void gather_nodes(
    const float* __restrict__ Xr, const float* __restrict__ Xi,
    const int* __restrict__ offsets, const int4* __restrict__ meta,
    float* __restrict__ out, int N, int E)
{
    const int n = blockIdx.x * 4 + (threadIdx.x >> 6);
    if (n >= N) return;
    const int lane = threadIdx.x & 63;
    const int start = offsets[n];
    const int end   = (n + 1 < N) ? offsets[n + 1] : E;
    float2 aR = make_float2(0.f, 0.f);
    float2 aI = make_float2(0.f, 0.f);
    for (int j = start; j < end; ++j) {
        const int4 m0 = meta[j];
        const float2 xr0 = *(const float2*)(Xr + (size_t)m0.x * CC + 2 * lane);
        const float2 xi0 = *(const float2*)(Xi + (size_t)m0.x * CC + 2 * lane);
        const float lr0 = __int_as_float(m0.y), li0 = __int_as_float(m0.z);
        aR.x += lr0 * xr0.x - li0 * xi0.x;
        aR.y += lr0 * xr0.y - li0 * xi0.y;
        aI.x += li0 * xr0.x + lr0 * xi0.x;
        aI.y += li0 * xr0.y + lr0 * xi0.y;
    }
    *(float2*)(out + (size_t)n * CC + 2 * lane) = aR;
    *(float2*)(out + ((size_t)n + N) * CC + 2 * lane) = aI;
}

__global__ __launch_bounds__(256) void scatter_edges(
    const float* __restrict__ Xr, const float* __restrict__ Xi,
    const float* __restrict__ Lr, const float* __restrict__ Li,
    const int* __restrict__ row, const int* __restrict__ col,
    float* __restrict__ out, int N, int E)
{
    const int e = blockIdx.x * 4 + (threadIdx.x >> 6);
    if (e >= E) return;
    const int lane = threadIdx.x & 63;
    const int r = row[e], c = col[e];
    const float lr = Lr[e];
    const float li = Li[e];
    const float2 xr = *(const float2*)(Xr + (size_t)c * CC + 2 * lane);
    const float2 xi = *(const float2*)(Xi + (size_t)c * CC + 2 * lane);
    float* pr = out + (size_t)r * CC + 2 * lane;
    float* pi = out + ((size_t)r + N) * CC + 2 * lane;
    unsafeAtomicAdd(pr,     lr * xr.x - li * xi.x);
    unsafeAtomicAdd(pr + 1, lr * xr.y - li * xi.y);
    unsafeAtomicAdd(pi,     li * xr.x + lr * xi.x);
    unsafeAtomicAdd(pi + 1, li * xr.y + lr * xi.y);
}

__global__ __launch_bounds__(256) void gemm_inplace(
    float* __restrict__ io, const float* __restrict__ W,
    const float* __restrict__ Xp, int N)
{
    __shared__ float Ws[64 * CC];
    __shared__ float AsT[CC][36];
    const int t = threadIdx.x;
    const int m0 = blockIdx.x * 32;

    for (int ch = t; ch < 1024; ch += 256) {
        const int r  = ch >> 5;
        const int k0 = (ch & 31) * 4;
        const int m  = m0 + r;
        float4 q = make_float4(0.f, 0.f, 0.f, 0.f);
        if (m < N) q = *(const float4*)(io + (size_t)m * CC + k0);
        AsT[k0 + 0][r] = q.x;
        AsT[k0 + 1][r] = q.y;
        AsT[k0 + 2][r] = q.z;
        AsT[k0 + 3][r] = q.w;
    }

    const int cg = t & 31;
    const int rs = t >> 5;
    float s[4][4];
    #pragma unroll
    for (int a = 0; a < 4; ++a)
        #pragma unroll
        for (int b = 0; b < 4; ++b) s[a][b] = 0.f;

    for (int kc = 0; kc < 2; ++kc) {
        __syncthreads();
        {
            const float4* src = (const float4*)(W + (size_t)kc * 64 * CC);
            float4* dst = (float4*)Ws;
            #pragma unroll
            for (int i = 0; i < 8; ++i) dst[t + 256 * i] = src[t + 256 * i];
        }
        __syncthreads();
        #pragma unroll 4
        for (int kk = 0; kk < 64; ++kk) {
            const int k = kc * 64 + kk;
            const float4 av = *(const float4*)&AsT[k][rs * 4];
            const float4 wv = *(const float4*)&Ws[kk * CC + cg * 4];
            const float ar[4] = {av.x, av.y, av.z, av.w};
            const float wc[4] = {wv.x, wv.y, wv.z, wv.w};
            #pragma unroll
            for (int a = 0; a < 4; ++a)
                #pragma unroll
                for (int b = 0; b < 4; ++b) s[a][b] += ar[a] * wc[b];
        }
    }

    #pragma unroll
    for (int a = 0; a < 4; ++a) {
        const int m = m0 + rs * 4 + a;
        if (m >= N) continue;
        const float4 xv = *(const float4*)(Xp + (size_t)m * CC + cg * 4);
        float4 o;
        o.x = s[a][0] + xv.x;
        o.y = s[a][1] + xv.y;
        o.z = s[a][2] + xv.z;
        o.w = s[a][3] + xv.w;
        *(float4*)(io + (size_t)m * CC + cg * 4) = o;
    }
}

// ===========================================================================
extern "C" void kernel_launch(void* const* d_in, const int* in_sizes, int n_in,
                              void* d_out, int out_size, void* d_ws, size_t ws_size,
                              hipStream_t stream)
{
    const float* Xr = (const float*)d_in[0];
    const float* Xi = (const float*)d_in[1];
    const float* Lr = (const float*)d_in[2];
    const float* Li = (const float*)d_in[3];
    const float* W  = (const float*)d_in[4];
    const int* row = (const int*)d_in[5];
    const int* col = (const int*)d_in[6];
    float* out = (float*)d_out;

    const int N = in_sizes[0] / CC;     // 50000
    const int E = in_sizes[2];          // 800000
    const int NB = (N + 255) / 256;     // scan blocks (196 <= 256)

    const size_t y_bytes    = (size_t)N * 256 * sizeof(unsigned short); // bf16 packed
    const size_t wt_bytes   = (size_t)CC * CC * sizeof(unsigned short); // 32 KB
    const size_t meta_bytes = (size_t)E * 16;
    const size_t int_bytes  = ((size_t)3 * N + 512) * sizeof(int);
    const size_t need_csr   = meta_bytes + int_bytes;
    const size_t need_fused = y_bytes + wt_bytes + need_csr;

    if (ws_size >= need_fused) {
        unsigned short* Y  = (unsigned short*)d_ws;
        unsigned short* Wt = (unsigned short*)((char*)d_ws + y_bytes);
        int4*  meta   = (int4*)((char*)d_ws + y_bytes + wt_bytes);
        int*   counts = (int*)((char*)d_ws + y_bytes + wt_bytes + meta_bytes);
        int*   cursor  = counts + N;
        int*   offsets = cursor + N;
        int*   bsum    = offsets + N;
        int*   bpre    = bsum + 256;

        hipMemsetAsync(counts, 0, (size_t)2 * N * sizeof(int), stream);
        hist_rows<<<dim3((E + 255) / 256), dim3(256), 0, stream>>>(row, counts, E);
        scan_block_reduce<<<dim3(NB), dim3(256), 0, stream>>>(counts, bsum, N);
        scan_bsum<<<dim3(1), dim3(256), 0, stream>>>(bsum, bpre, NB);
        scan_final<<<dim3(NB), dim3(256), 0, stream>>>(counts, bpre, offsets, N);
        fill_csr<<<dim3((E + 255) / 256), dim3(256), 0, stream>>>(
            row, col, Lr, Li, offsets, cursor, meta, E);
        conv_w<<<dim3((CC * CC + 255) / 256), dim3(256), 0, stream>>>(W, Wt);
        gemm_xw_mfma<<<dim3((2 * N + 63) / 64), dim3(256), 0, stream>>>(
            Xr, Xi, Wt, Y, N);
        gather_fused<<<dim3((N + 3) / 4), dim3(256), 0, stream>>>(
            Y, Xr, Xi, offsets, meta, out, N, E);
    } else if (ws_size >= need_csr) {
        int4* meta    = (int4*)d_ws;
        int*  counts  = (int*)((char*)d_ws + meta_bytes);
        int*  cursor  = counts + N;
        int*  offsets = cursor + N;
        int*  bsum    = offsets + N;
        int*  bpre    = bsum + 256;

        hipMemsetAsync(counts, 0, (size_t)2 * N * sizeof(int), stream);
        hist_rows<<<dim3((E + 255) / 256), dim3(256), 0, stream>>>(row, counts, E);
        scan_block_reduce<<<dim3(NB), dim3(256), 0, stream>>>(counts, bsum, N);
        scan_bsum<<<dim3(1), dim3(256), 0, stream>>>(bsum, bpre, NB);
        scan_final<<<dim3(NB), dim3(256), 0, stream>>>(counts, bpre, offsets, N);
        fill_csr<<<dim3((E + 255) / 256), dim3(256), 0, stream>>>(
            row, col, Lr, Li, offsets, cursor, meta, E);
        gather_nodes<<<dim3((N + 3) / 4), dim3(256), 0, stream>>>(
            Xr, Xi, offsets, meta, out, N, E);
        gemm_inplace<<<dim3((N + 31) / 32), dim3(256), 0, stream>>>(out, W, Xr, N);
        gemm_inplace<<<dim3((N + 31) / 32), dim3(256), 0, stream>>>(
            out + (size_t)N * CC, W, Xi, N);
    } else {
        hipMemsetAsync(out, 0, (size_t)2 * N * CC * sizeof(float), stream);
        scatter_edges<<<dim3((E + 3) / 4), dim3(256), 0, stream>>>(
            Xr, Xi, Lr, Li, row, col, out, N, E);
        gemm_inplace<<<dim3((N + 31) / 32), dim3(256), 0, stream>>>(out, W, Xr, N);
        gemm_inplace<<<dim3((N + 31) / 32), dim3(256), 0, stream>>>(
            out + (size_t)N * CC, W, Xi, N);
    }
}

// Round 9
// 253.029 us; speedup vs baseline: 1.5584x; 1.1100x over previous
//
#include <hip/hip_runtime.h>
#include <cstddef>

#define CC 128  // channels

typedef __attribute__((ext_vector_type(8))) short bf16x8;
typedef __attribute__((ext_vector_type(4))) float f32x4;

// ===========================================================================
// CSR build: histogram(+rank) -> 3-kernel parallel scan -> atomic-free fill
// ===========================================================================

// 4 edges/thread. rank[e] = this edge's arrival index within its row --
// the atomicAdd return we previously threw away. This makes fill_csr
// atomic-free (no 800K atomic-with-return round trips on the fabric).
__global__ __launch_bounds__(256) void hist_rank(
    const int* __restrict__ row, int* __restrict__ counts,
    int* __restrict__ rank, int E)
{
    const int base = (blockIdx.x * 256 + threadIdx.x) * 4;
    if (base + 3 < E) {
        const int4 r4 = *(const int4*)(row + base);
        int4 k4;
        k4.x = atomicAdd(counts + r4.x, 1);
        k4.y = atomicAdd(counts + r4.y, 1);
        k4.z = atomicAdd(counts + r4.z, 1);
        k4.w = atomicAdd(counts + r4.w, 1);
        *(int4*)(rank + base) = k4;
    } else {
        for (int e = base; e < E; ++e)
            rank[e] = atomicAdd(counts + row[e], 1);
    }
}

// Per-block sum of 256 counts -> bsum[block]
__global__ __launch_bounds__(256) void scan_block_reduce(
    const int* __restrict__ counts, int* __restrict__ bsum, int N)
{
    __shared__ int s[256];
    const int t = threadIdx.x;
    const int idx = blockIdx.x * 256 + t;
    s[t] = (idx < N) ? counts[idx] : 0;
    __syncthreads();
    #pragma unroll
    for (int off = 128; off > 0; off >>= 1) {
        if (t < off) s[t] += s[t + off];
        __syncthreads();
    }
    if (t == 0) bsum[blockIdx.x] = s[0];
}

// Exclusive scan of NB (<=256) block sums, single block.
__global__ __launch_bounds__(256) void scan_bsum(
    const int* __restrict__ bsum, int* __restrict__ bpre, int NB)
{
    __shared__ int s[256];
    const int t = threadIdx.x;
    s[t] = (t < NB) ? bsum[t] : 0;
    __syncthreads();
    #pragma unroll
    for (int off = 1; off < 256; off <<= 1) {
        const int v = s[t];
        const int u = (t >= off) ? s[t - off] : 0;
        __syncthreads();
        s[t] = v + u;
        __syncthreads();
    }
    if (t < NB) bpre[t] = t ? s[t - 1] : 0;
}

// Block-local exclusive scan + block prefix -> offsets
__global__ __launch_bounds__(256) void scan_final(
    const int* __restrict__ counts, const int* __restrict__ bpre,
    int* __restrict__ offsets, int N)
{
    __shared__ int s[256];
    const int t = threadIdx.x;
    const int idx = blockIdx.x * 256 + t;
    const int v = (idx < N) ? counts[idx] : 0;
    s[t] = v;
    __syncthreads();
    #pragma unroll
    for (int off = 1; off < 256; off <<= 1) {
        const int a = s[t];
        const int u = (t >= off) ? s[t - off] : 0;
        __syncthreads();
        s[t] = a + u;
        __syncthreads();
    }
    if (idx < N) offsets[idx] = bpre[blockIdx.x] + s[t] - v;  // exclusive
}

// Atomic-free scatter: pos = offsets[row] + rank. 4 edges/thread, vector loads.
__global__ __launch_bounds__(256) void fill_csr_rank(
    const int* __restrict__ row, const int* __restrict__ col,
    const float* __restrict__ Lr, const float* __restrict__ Li,
    const int* __restrict__ offsets, const int* __restrict__ rank,
    int4* __restrict__ meta, int E)
{
    const int base = (blockIdx.x * 256 + threadIdx.x) * 4;
    if (base + 3 < E) {
        const int4   r4 = *(const int4*)(row + base);
        const int4   c4 = *(const int4*)(col + base);
        const float4 a4 = *(const float4*)(Lr + base);
        const float4 b4 = *(const float4*)(Li + base);
        const int4   k4 = *(const int4*)(rank + base);
        meta[offsets[r4.x] + k4.x] =
            make_int4(c4.x, __float_as_int(a4.x), __float_as_int(b4.x), 0);
        meta[offsets[r4.y] + k4.y] =
            make_int4(c4.y, __float_as_int(a4.y), __float_as_int(b4.y), 0);
        meta[offsets[r4.z] + k4.z] =
            make_int4(c4.z, __float_as_int(a4.z), __float_as_int(b4.z), 0);
        meta[offsets[r4.w] + k4.w] =
            make_int4(c4.w, __float_as_int(a4.w), __float_as_int(b4.w), 0);
    } else {
        for (int e = base; e < E; ++e)
            meta[offsets[row[e]] + rank[e]] =
                make_int4(col[e], __float_as_int(Lr[e]), __float_as_int(Li[e]), 0);
    }
}

// fp32 -> bf16 (round-to-nearest-even on the bit pattern)
__device__ __forceinline__ unsigned short f2bf(float f)
{
    unsigned int u = __float_as_uint(f);
    u = (u + 0x7fffu + ((u >> 16) & 1u)) >> 16;
    return (unsigned short)u;
}

__device__ __forceinline__ unsigned int pack2(float a, float b)
{
    return (unsigned int)f2bf(a) | ((unsigned int)f2bf(b) << 16);
}

// ===========================================================================
// One-shot: Wt[n][k] = bf16(W[k][n]), PRE-SWIZZLED for LDS b128 reads.
// ===========================================================================
__global__ __launch_bounds__(256) void conv_w(
    const float* __restrict__ W, unsigned short* __restrict__ Wt)
{
    const int idx = blockIdx.x * 256 + threadIdx.x;   // 64 blocks x 256
    if (idx >= CC * CC) return;
    const int k = idx >> 7;          // coalesced read of W[k][n]
    const int n = idx & 127;
    const unsigned int sw = ((unsigned)(2 * k) ^ (((unsigned)n & 7u) << 4)) >> 1;
    Wt[(size_t)n * 128 + sw] = f2bf(W[idx]);
}

// ===========================================================================
// Y = [Xr;Xi] @ W via bf16 MFMA (fp32 accumulate), Y packed bf16 [N][256].
// (unchanged from R8; verified, ~31us pipeline win)
// ===========================================================================
__global__ __launch_bounds__(256) void gemm_xw_mfma(
    const float* __restrict__ Xr, const float* __restrict__ Xi,
    const unsigned short* __restrict__ Wt,   // pre-swizzled bf16 [128][128]
    unsigned short* __restrict__ Y, int N)
{
    __shared__ unsigned short Bs[128 * 128];   // 32 KB (Wt, swizzled rows n)
    __shared__ unsigned short As[64 * 128];    // 16 KB (A tile, swizzled rows r)
    const int t = threadIdx.x;
    const int m0 = blockIdx.x * 64;
    const int M = 2 * N;

    // stage Wt: straight 32KB copy (already swizzled)
    {
        const uint4* src = (const uint4*)Wt;
        uint4* dst = (uint4*)Bs;
        #pragma unroll
        for (int i = 0; i < 8; ++i) dst[t + 256 * i] = src[t + 256 * i];
    }
    // stage A: 1024 x 16B blocks; fp32 -> bf16 convert, swizzled write
    #pragma unroll
    for (int i = 0; i < 4; ++i) {
        const int blk = t + 256 * i;
        const int r  = blk >> 4;          // 0..63
        const int k0 = (blk & 15) * 8;    // 0..120
        const int m  = m0 + r;
        float4 q0 = make_float4(0.f, 0.f, 0.f, 0.f);
        float4 q1 = make_float4(0.f, 0.f, 0.f, 0.f);
        if (m < M) {
            const float* src = (m < N) ? (Xr + (size_t)m * CC)
                                       : (Xi + (size_t)(m - N) * CC);
            q0 = *(const float4*)(src + k0);
            q1 = *(const float4*)(src + k0 + 4);
        }
        uint4 h;
        h.x = pack2(q0.x, q0.y);
        h.y = pack2(q0.z, q0.w);
        h.z = pack2(q1.x, q1.y);
        h.w = pack2(q1.z, q1.w);
        const int byte = r * 256 + ((2 * k0) ^ ((r & 7) << 4));
        *(uint4*)((char*)As + byte) = h;
    }
    __syncthreads();

    const int w = t >> 6, lane = t & 63;
    const int wr = w >> 1, wc = w & 1;     // 2x2 wave grid
    const int r0 = wr * 32;                // local row base (32 rows/wave)
    const int c0 = wc * 64;                // local col base (64 cols/wave)
    const int lr = lane & 15;              // frag row/col index
    const int lk = lane >> 4;              // k-group (0..3)

    f32x4 acc[2][4];
    #pragma unroll
    for (int a = 0; a < 2; ++a)
        #pragma unroll
        for (int b = 0; b < 4; ++b)
            acc[a][b] = (f32x4){0.f, 0.f, 0.f, 0.f};

    #pragma unroll
    for (int kk = 0; kk < 4; ++kk) {
        const int kbase = kk * 32 + lk * 8;
        bf16x8 afrag[2];
        #pragma unroll
        for (int at = 0; at < 2; ++at) {
            const int row = r0 + at * 16 + lr;
            afrag[at] = *(const bf16x8*)((const char*)As +
                row * 256 + ((2 * kbase) ^ ((row & 7) << 4)));
        }
        #pragma unroll
        for (int bt = 0; bt < 4; ++bt) {
            const int col = c0 + bt * 16 + lr;
            const bf16x8 bfrag = *(const bf16x8*)((const char*)Bs +
                col * 256 + ((2 * kbase) ^ ((col & 7) << 4)));
            acc[0][bt] = __builtin_amdgcn_mfma_f32_16x16x32_bf16(
                afrag[0], bfrag, acc[0][bt], 0, 0, 0);
            acc[1][bt] = __builtin_amdgcn_mfma_f32_16x16x32_bf16(
                afrag[1], bfrag, acc[1][bt], 0, 0, 0);
        }
    }

    // store: C/D lane mapping col=lane&15, row=(lane>>4)*4+v
    #pragma unroll
    for (int at = 0; at < 2; ++at) {
        #pragma unroll
        for (int v = 0; v < 4; ++v) {
            const int m = m0 + r0 + at * 16 + lk * 4 + v;
            if (m >= M) continue;
            const int node = (m < N) ? m : m - N;
            const int half = (m < N) ? 0 : 128;
            unsigned short* dst = Y + (size_t)node * 256 + half;
            #pragma unroll
            for (int bt = 0; bt < 4; ++bt)
                dst[c0 + bt * 16 + lr] = f2bf(acc[at][bt][v]);
        }
    }
}

// ===========================================================================
// Fused gather: out[n] = sum_e L_e * Ybf16[col_e] + X[n]  (complex),
// 1 wave/node, 2 ch/lane, 8-edge chunks. (unchanged from R8, 74us)
// ===========================================================================
__device__ __forceinline__ void cmadd_bf(
    const int4 m, const unsigned int ur, const unsigned int ui,
    float2& aR, float2& aI)
{
    const float lr = __int_as_float(m.y);
    const float li = __int_as_float(m.z);
    const float yrx = __uint_as_float(ur << 16);
    const float yry = __uint_as_float(ur & 0xFFFF0000u);
    const float yix = __uint_as_float(ui << 16);
    const float yiy = __uint_as_float(ui & 0xFFFF0000u);
    aR.x += lr * yrx - li * yix;
    aR.y += lr * yry - li * yiy;
    aI.x += li * yrx + lr * yix;
    aI.y += li * yry + lr * yiy;
}

__device__ __forceinline__ void edge_acc(
    const int4 m, const unsigned short* __restrict__ Y,
    int lane, float2& aR, float2& aI)
{
    const unsigned short* b = Y + (size_t)m.x * 256 + 2 * lane;
    const unsigned int ur = *(const unsigned int*)(b);
    const unsigned int ui = *(const unsigned int*)(b + 128);
    cmadd_bf(m, ur, ui, aR, aI);
}

__global__ __launch_bounds__(256) void gather_fused(
    const unsigned short* __restrict__ Y,  // packed bf16 [N][256]
    const float* __restrict__ Xr, const float* __restrict__ Xi,
    const int* __restrict__ offsets, const int4* __restrict__ meta,
    float* __restrict__ out, int N, int E)
{
    const int n = blockIdx.x * 4 + (threadIdx.x >> 6);
    if (n >= N) return;
    const int lane = threadIdx.x & 63;
    const int start = offsets[n];
    const int end   = (n + 1 < N) ? offsets[n + 1] : E;
    const int Em1 = E - 1;

    // residual init
    float2 aR = *(const float2*)(Xr + (size_t)n * CC + 2 * lane);
    float2 aI = *(const float2*)(Xi + (size_t)n * CC + 2 * lane);

    int4 m0 = meta[min(start + 0, Em1)];
    int4 m1 = meta[min(start + 1, Em1)];
    int4 m2 = meta[min(start + 2, Em1)];
    int4 m3 = meta[min(start + 3, Em1)];
    int4 m4 = meta[min(start + 4, Em1)];
    int4 m5 = meta[min(start + 5, Em1)];
    int4 m6 = meta[min(start + 6, Em1)];
    int4 m7 = meta[min(start + 7, Em1)];

    int j = start;
    for (; j + 8 <= end; j += 8) {
        // prefetch next chunk's meta (wave-uniform)
        const int4 n0 = meta[min(j +  8, Em1)];
        const int4 n1 = meta[min(j +  9, Em1)];
        const int4 n2 = meta[min(j + 10, Em1)];
        const int4 n3 = meta[min(j + 11, Em1)];
        const int4 n4 = meta[min(j + 12, Em1)];
        const int4 n5 = meta[min(j + 13, Em1)];
        const int4 n6 = meta[min(j + 14, Em1)];
        const int4 n7 = meta[min(j + 15, Em1)];
        // 16 independent dword loads from 8 contiguous 512B rows
        const unsigned short* b0 = Y + (size_t)m0.x * 256 + 2 * lane;
        const unsigned short* b1 = Y + (size_t)m1.x * 256 + 2 * lane;
        const unsigned short* b2 = Y + (size_t)m2.x * 256 + 2 * lane;
        const unsigned short* b3 = Y + (size_t)m3.x * 256 + 2 * lane;
        const unsigned short* b4 = Y + (size_t)m4.x * 256 + 2 * lane;
        const unsigned short* b5 = Y + (size_t)m5.x * 256 + 2 * lane;
        const unsigned short* b6 = Y + (size_t)m6.x * 256 + 2 * lane;
        const unsigned short* b7 = Y + (size_t)m7.x * 256 + 2 * lane;
        const unsigned int ur0 = *(const unsigned int*)(b0);
        const unsigned int ui0 = *(const unsigned int*)(b0 + 128);
        const unsigned int ur1 = *(const unsigned int*)(b1);
        const unsigned int ui1 = *(const unsigned int*)(b1 + 128);
        const unsigned int ur2 = *(const unsigned int*)(b2);
        const unsigned int ui2 = *(const unsigned int*)(b2 + 128);
        const unsigned int ur3 = *(const unsigned int*)(b3);
        const unsigned int ui3 = *(const unsigned int*)(b3 + 128);
        const unsigned int ur4 = *(const unsigned int*)(b4);
        const unsigned int ui4 = *(const unsigned int*)(b4 + 128);
        const unsigned int ur5 = *(const unsigned int*)(b5);
        const unsigned int ui5 = *(const unsigned int*)(b5 + 128);
        const unsigned int ur6 = *(const unsigned int*)(b6);
        const unsigned int ui6 = *(const unsigned int*)(b6 + 128);
        const unsigned int ur7 = *(const unsigned int*)(b7);
        const unsigned int ui7 = *(const unsigned int*)(b7 + 128);

        cmadd_bf(m0, ur0, ui0, aR, aI);
        cmadd_bf(m1, ur1, ui1, aR, aI);
        cmadd_bf(m2, ur2, ui2, aR, aI);
        cmadd_bf(m3, ur3, ui3, aR, aI);
        cmadd_bf(m4, ur4, ui4, aR, aI);
        cmadd_bf(m5, ur5, ui5, aR, aI);
        cmadd_bf(m6, ur6, ui6, aR, aI);
        cmadd_bf(m7, ur7, ui7, aR, aI);

        m0 = n0; m1 = n1; m2 = n2; m3 = n3;
        m4 = n4; m5 = n5; m6 = n6; m7 = n7;
    }
    const int r = end - j;   // 0..7 remaining edges, meta already in m0..m6
    if (r > 0) edge_acc(m0, Y, lane, aR, aI);
    if (r > 1) edge_acc(m1, Y, lane, aR, aI);
    if (r > 2) edge_acc(m2, Y, lane, aR, aI);
    if (r > 3) edge_acc(m3, Y, lane, aR, aI);
    if (r > 4) edge_acc(m4, Y, lane, aR, aI);
    if (r > 5) edge_acc(m5, Y, lane, aR, aI);
    if (r > 6) edge_acc(m6, Y, lane, aR, aI);

    *(float2*)(out + (size_t)n * CC + 2 * lane) = aR;
    *(float2*)(out + ((size_t)n + N) * CC + 2 * lane) = aI;
}

// ===========================================================================
// Fallback kernels (full fp32 paths)
// ===========================================================================
__global__ __launch_bounds__(256) void gather_nodes(
    const float* __restrict__ Xr, const float* __restrict__ Xi,
    const int* __restrict__ offsets, const int4* __restrict__ meta,
    float* __restrict__ out, int N, int E)
{
    const int n = blockIdx.x * 4 + (threadIdx.x >> 6);
    if (n >= N) return;
    const int lane = threadIdx.x & 63;
    const int start = offsets[n];
    const int end   = (n + 1 < N) ? offsets[n + 1] : E;
    float2 aR = make_float2(0.f, 0.f);
    float2 aI = make_float2(0.f, 0.f);
    for (int j = start; j < end; ++j) {
        const int4 m0 = meta[j];
        const float2 xr0 = *(const float2*)(Xr + (size_t)m0.x * CC + 2 * lane);
        const float2 xi0 = *(const float2*)(Xi + (size_t)m0.x * CC + 2 * lane);
        const float lr0 = __int_as_float(m0.y), li0 = __int_as_float(m0.z);
        aR.x += lr0 * xr0.x - li0 * xi0.x;
        aR.y += lr0 * xr0.y - li0 * xi0.y;
        aI.x += li0 * xr0.x + lr0 * xi0.x;
        aI.y += li0 * xr0.y + lr0 * xi0.y;
    }
    *(float2*)(out + (size_t)n * CC + 2 * lane) = aR;
    *(float2*)(out + ((size_t)n + N) * CC + 2 * lane) = aI;
}

__global__ __launch_bounds__(256) void scatter_edges(
    const float* __restrict__ Xr, const float* __restrict__ Xi,
    const float* __restrict__ Lr, const float* __restrict__ Li,
    const int* __restrict__ row, const int* __restrict__ col,
    float* __restrict__ out, int N, int E)
{
    const int e = blockIdx.x * 4 + (threadIdx.x >> 6);
    if (e >= E) return;
    const int lane = threadIdx.x & 63;
    const int r = row[e], c = col[e];
    const float lr = Lr[e];
    const float li = Li[e];
    const float2 xr = *(const float2*)(Xr + (size_t)c * CC + 2 * lane);
    const float2 xi = *(const float2*)(Xi + (size_t)c * CC + 2 * lane);
    float* pr = out + (size_t)r * CC + 2 * lane;
    float* pi = out + ((size_t)r + N) * CC + 2 * lane;
    unsafeAtomicAdd(pr,     lr * xr.x - li * xi.x);
    unsafeAtomicAdd(pr + 1, lr * xr.y - li * xi.y);
    unsafeAtomicAdd(pi,     li * xr.x + lr * xi.x);
    unsafeAtomicAdd(pi + 1, li * xr.y + lr * xi.y);
}

__global__ __launch_bounds__(256) void gemm_inplace(
    float* __restrict__ io, const float* __restrict__ W,
    const float* __restrict__ Xp, int N)
{
    __shared__ float Ws[64 * CC];
    __shared__ float AsT[CC][36];
    const int t = threadIdx.x;
    const int m0 = blockIdx.x * 32;

    for (int ch = t; ch < 1024; ch += 256) {
        const int r  = ch >> 5;
        const int k0 = (ch & 31) * 4;
        const int m  = m0 + r;
        float4 q = make_float4(0.f, 0.f, 0.f, 0.f);
        if (m < N) q = *(const float4*)(io + (size_t)m * CC + k0);
        AsT[k0 + 0][r] = q.x;
        AsT[k0 + 1][r] = q.y;
        AsT[k0 + 2][r] = q.z;
        AsT[k0 + 3][r] = q.w;
    }

    const int cg = t & 31;
    const int rs = t >> 5;
    float s[4][4];
    #pragma unroll
    for (int a = 0; a < 4; ++a)
        #pragma unroll
        for (int b = 0; b < 4; ++b) s[a][b] = 0.f;

    for (int kc = 0; kc < 2; ++kc) {
        __syncthreads();
        {
            const float4* src = (const float4*)(W + (size_t)kc * 64 * CC);
            float4* dst = (float4*)Ws;
            #pragma unroll
            for (int i = 0; i < 8; ++i) dst[t + 256 * i] = src[t + 256 * i];
        }
        __syncthreads();
        #pragma unroll 4
        for (int kk = 0; kk < 64; ++kk) {
            const int k = kc * 64 + kk;
            const float4 av = *(const float4*)&AsT[k][rs * 4];
            const float4 wv = *(const float4*)&Ws[kk * CC + cg * 4];
            const float ar[4] = {av.x, av.y, av.z, av.w};
            const float wc[4] = {wv.x, wv.y, wv.z, wv.w};
            #pragma unroll
            for (int a = 0; a < 4; ++a)
                #pragma unroll
                for (int b = 0; b < 4; ++b) s[a][b] += ar[a] * wc[b];
        }
    }

    #pragma unroll
    for (int a = 0; a < 4; ++a) {
        const int m = m0 + rs * 4 + a;
        if (m >= N) continue;
        const float4 xv = *(const float4*)(Xp + (size_t)m * CC + cg * 4);
        float4 o;
        o.x = s[a][0] + xv.x;
        o.y = s[a][1] + xv.y;
        o.z = s[a][2] + xv.z;
        o.w = s[a][3] + xv.w;
        *(float4*)(io + (size_t)m * CC + cg * 4) = o;
    }
}

// ===========================================================================
extern "C" void kernel_launch(void* const* d_in, const int* in_sizes, int n_in,
                              void* d_out, int out_size, void* d_ws, size_t ws_size,
                              hipStream_t stream)
{
    const float* Xr = (const float*)d_in[0];
    const float* Xi = (const float*)d_in[1];
    const float* Lr = (const float*)d_in[2];
    const float* Li = (const float*)d_in[3];
    const float* W  = (const float*)d_in[4];
    const int* row = (const int*)d_in[5];
    const int* col = (const int*)d_in[6];
    float* out = (float*)d_out;

    const int N = in_sizes[0] / CC;     // 50000
    const int E = in_sizes[2];          // 800000
    const int NB = (N + 255) / 256;     // scan blocks (196 <= 256)
    const int EB4 = ((E + 3) / 4 + 255) / 256;  // 4-edge/thread grids

    const size_t y_bytes    = (size_t)N * 256 * sizeof(unsigned short); // bf16 packed
    const size_t wt_bytes   = (size_t)CC * CC * sizeof(unsigned short); // 32 KB
    const size_t meta_bytes = (size_t)E * 16;
    const size_t int_bytes  = ((size_t)2 * N + 512 + E) * sizeof(int);  // counts,offsets,bsum,bpre,rank
    const size_t need_csr   = meta_bytes + int_bytes;
    const size_t need_fused = y_bytes + wt_bytes + need_csr;

    if (ws_size >= need_fused) {
        unsigned short* Y  = (unsigned short*)d_ws;
        unsigned short* Wt = (unsigned short*)((char*)d_ws + y_bytes);
        int4*  meta   = (int4*)((char*)d_ws + y_bytes + wt_bytes);
        int*   counts = (int*)((char*)d_ws + y_bytes + wt_bytes + meta_bytes);
        int*   offsets = counts + N;
        int*   bsum    = offsets + N;
        int*   bpre    = bsum + 256;
        int*   rank    = bpre + 256;

        hipMemsetAsync(counts, 0, (size_t)N * sizeof(int), stream);
        hist_rank<<<dim3(EB4), dim3(256), 0, stream>>>(row, counts, rank, E);
        scan_block_reduce<<<dim3(NB), dim3(256), 0, stream>>>(counts, bsum, N);
        scan_bsum<<<dim3(1), dim3(256), 0, stream>>>(bsum, bpre, NB);
        scan_final<<<dim3(NB), dim3(256), 0, stream>>>(counts, bpre, offsets, N);
        fill_csr_rank<<<dim3(EB4), dim3(256), 0, stream>>>(
            row, col, Lr, Li, offsets, rank, meta, E);
        conv_w<<<dim3((CC * CC + 255) / 256), dim3(256), 0, stream>>>(W, Wt);
        gemm_xw_mfma<<<dim3((2 * N + 63) / 64), dim3(256), 0, stream>>>(
            Xr, Xi, Wt, Y, N);
        gather_fused<<<dim3((N + 3) / 4), dim3(256), 0, stream>>>(
            Y, Xr, Xi, offsets, meta, out, N, E);
    } else if (ws_size >= need_csr) {
        int4* meta    = (int4*)d_ws;
        int*  counts  = (int*)((char*)d_ws + meta_bytes);
        int*  offsets = counts + N;
        int*  bsum    = offsets + N;
        int*  bpre    = bsum + 256;
        int*  rank    = bpre + 256;

        hipMemsetAsync(counts, 0, (size_t)N * sizeof(int), stream);
        hist_rank<<<dim3(EB4), dim3(256), 0, stream>>>(row, counts, rank, E);
        scan_block_reduce<<<dim3(NB), dim3(256), 0, stream>>>(counts, bsum, N);
        scan_bsum<<<dim3(1), dim3(256), 0, stream>>>(bsum, bpre, NB);
        scan_final<<<dim3(NB), dim3(256), 0, stream>>>(counts, bpre, offsets, N);
        fill_csr_rank<<<dim3(EB4), dim3(256), 0, stream>>>(
            row, col, Lr, Li, offsets, rank, meta, E);
        gather_nodes<<<dim3((N + 3) / 4), dim3(256), 0, stream>>>(
            Xr, Xi, offsets, meta, out, N, E);
        gemm_inplace<<<dim3((N + 31) / 32), dim3(256), 0, stream>>>(out, W, Xr, N);
        gemm_inplace<<<dim3((N + 31) / 32), dim3(256), 0, stream>>>(
            out + (size_t)N * CC, W, Xi, N);
    } else {
        hipMemsetAsync(out, 0, (size_t)2 * N * CC * sizeof(float), stream);
        scatter_edges<<<dim3((E + 3) / 4), dim3(256), 0, stream>>>(
            Xr, Xi, Lr, Li, row, col, out, N, E);
        gemm_inplace<<<dim3((N + 31) / 32), dim3(256), 0, stream>>>(out, W, Xr, N);
        gemm_inplace<<<dim3((N + 31) / 32), dim3(256), 0, stream>>>(
            out + (size_t)N * CC, W, Xi, N);
    }
}

// Round 10
// 251.461 us; speedup vs baseline: 1.5681x; 1.0062x over previous
//
#include <hip/hip_runtime.h>
#include <cstddef>

#define CC 128  // channels

typedef __attribute__((ext_vector_type(8))) short bf16x8;
typedef __attribute__((ext_vector_type(4))) float f32x4;

// ===========================================================================
// CSR build: 4-bank replicated histogram(+rank) -> scan (+replica bases)
//            -> atomic-free fill.
// Edge e uses bank (e&3): per-counter contention /4, and a thread's 4
// atomics hit 4 different banks (no intra-thread same-line serialization).
// pos = rbase[e&3][row] + rank[e]; rbase[0] IS the offsets array.
// ===========================================================================

__global__ __launch_bounds__(256) void hist_rank(
    const int* __restrict__ row, int* __restrict__ counts,  // [4][N]
    int* __restrict__ rank, int N, int E)
{
    const int base = (blockIdx.x * 256 + threadIdx.x) * 4;
    if (base + 3 < E) {
        const int4 r4 = *(const int4*)(row + base);
        int4 k4;
        k4.x = atomicAdd(counts + 0 * N + r4.x, 1);
        k4.y = atomicAdd(counts + 1 * N + r4.y, 1);
        k4.z = atomicAdd(counts + 2 * N + r4.z, 1);
        k4.w = atomicAdd(counts + 3 * N + r4.w, 1);
        *(int4*)(rank + base) = k4;
    } else {
        for (int e = base; e < E; ++e)
            rank[e] = atomicAdd(counts + (size_t)(e & 3) * N + row[e], 1);
    }
}

// Per-block sum of 256 row-totals (4 banks summed) -> bsum[block]
__global__ __launch_bounds__(256) void scan_block_reduce(
    const int* __restrict__ counts, int* __restrict__ bsum, int N)
{
    __shared__ int s[256];
    const int t = threadIdx.x;
    const int idx = blockIdx.x * 256 + t;
    int v = 0;
    if (idx < N)
        v = counts[idx] + counts[N + idx] + counts[2 * N + idx]
          + counts[3 * N + idx];
    s[t] = v;
    __syncthreads();
    #pragma unroll
    for (int off = 128; off > 0; off >>= 1) {
        if (t < off) s[t] += s[t + off];
        __syncthreads();
    }
    if (t == 0) bsum[blockIdx.x] = s[0];
}

// Exclusive scan of NB (<=256) block sums, single block.
__global__ __launch_bounds__(256) void scan_bsum(
    const int* __restrict__ bsum, int* __restrict__ bpre, int NB)
{
    __shared__ int s[256];
    const int t = threadIdx.x;
    s[t] = (t < NB) ? bsum[t] : 0;
    __syncthreads();
    #pragma unroll
    for (int off = 1; off < 256; off <<= 1) {
        const int v = s[t];
        const int u = (t >= off) ? s[t - off] : 0;
        __syncthreads();
        s[t] = v + u;
        __syncthreads();
    }
    if (t < NB) bpre[t] = t ? s[t - 1] : 0;
}

// Block-local exclusive scan of row totals + block prefix -> replica bases.
// rbase[0][n] = offsets[n] (exclusive row start); rbase[q] = rbase[q-1]+c_{q-1}.
__global__ __launch_bounds__(256) void scan_final(
    const int* __restrict__ counts, const int* __restrict__ bpre,
    int* __restrict__ rbase, int N)
{
    __shared__ int s[256];
    const int t = threadIdx.x;
    const int idx = blockIdx.x * 256 + t;
    int c0 = 0, c1 = 0, c2 = 0, c3 = 0;
    if (idx < N) {
        c0 = counts[idx];
        c1 = counts[N + idx];
        c2 = counts[2 * N + idx];
        c3 = counts[3 * N + idx];
    }
    const int v = c0 + c1 + c2 + c3;
    s[t] = v;
    __syncthreads();
    #pragma unroll
    for (int off = 1; off < 256; off <<= 1) {
        const int a = s[t];
        const int u = (t >= off) ? s[t - off] : 0;
        __syncthreads();
        s[t] = a + u;
        __syncthreads();
    }
    if (idx < N) {
        const int off = bpre[blockIdx.x] + s[t] - v;  // exclusive row start
        rbase[idx]         = off;
        rbase[N + idx]     = off + c0;
        rbase[2 * N + idx] = off + c0 + c1;
        rbase[3 * N + idx] = off + c0 + c1 + c2;
    }
}

// Atomic-free scatter: pos = rbase[e&3][row] + rank[e]. 4 edges/thread.
__global__ __launch_bounds__(256) void fill_csr_rank(
    const int* __restrict__ row, const int* __restrict__ col,
    const float* __restrict__ Lr, const float* __restrict__ Li,
    const int* __restrict__ rbase, const int* __restrict__ rank,
    int4* __restrict__ meta, int N, int E)
{
    const int base = (blockIdx.x * 256 + threadIdx.x) * 4;
    if (base + 3 < E) {               // base%4==0 -> reps are exactly 0,1,2,3
        const int4   r4 = *(const int4*)(row + base);
        const int4   c4 = *(const int4*)(col + base);
        const float4 a4 = *(const float4*)(Lr + base);
        const float4 b4 = *(const float4*)(Li + base);
        const int4   k4 = *(const int4*)(rank + base);
        meta[rbase[r4.x] + k4.x] =
            make_int4(c4.x, __float_as_int(a4.x), __float_as_int(b4.x), 0);
        meta[rbase[N + r4.y] + k4.y] =
            make_int4(c4.y, __float_as_int(a4.y), __float_as_int(b4.y), 0);
        meta[rbase[2 * N + r4.z] + k4.z] =
            make_int4(c4.z, __float_as_int(a4.z), __float_as_int(b4.z), 0);
        meta[rbase[3 * N + r4.w] + k4.w] =
            make_int4(c4.w, __float_as_int(a4.w), __float_as_int(b4.w), 0);
    } else {
        for (int e = base; e < E; ++e)
            meta[rbase[(size_t)(e & 3) * N + row[e]] + rank[e]] =
                make_int4(col[e], __float_as_int(Lr[e]), __float_as_int(Li[e]), 0);
    }
}

// fp32 -> bf16 (round-to-nearest-even on the bit pattern)
__device__ __forceinline__ unsigned short f2bf(float f)
{
    unsigned int u = __float_as_uint(f);
    u = (u + 0x7fffu + ((u >> 16) & 1u)) >> 16;
    return (unsigned short)u;
}

__device__ __forceinline__ unsigned int pack2(float a, float b)
{
    return (unsigned int)f2bf(a) | ((unsigned int)f2bf(b) << 16);
}

// ===========================================================================
// One-shot: Wt[n][k] = bf16(W[k][n]), PRE-SWIZZLED for LDS b128 reads.
// ===========================================================================
__global__ __launch_bounds__(256) void conv_w(
    const float* __restrict__ W, unsigned short* __restrict__ Wt)
{
    const int idx = blockIdx.x * 256 + threadIdx.x;   // 64 blocks x 256
    if (idx >= CC * CC) return;
    const int k = idx >> 7;          // coalesced read of W[k][n]
    const int n = idx & 127;
    const unsigned int sw = ((unsigned)(2 * k) ^ (((unsigned)n & 7u) << 4)) >> 1;
    Wt[(size_t)n * 128 + sw] = f2bf(W[idx]);
}

// ===========================================================================
// Y = [Xr;Xi] @ W via bf16 MFMA (fp32 accumulate), Y packed bf16 [N][256].
// (verified R8/R9)
// ===========================================================================
__global__ __launch_bounds__(256) void gemm_xw_mfma(
    const float* __restrict__ Xr, const float* __restrict__ Xi,
    const unsigned short* __restrict__ Wt,   // pre-swizzled bf16 [128][128]
    unsigned short* __restrict__ Y, int N)
{
    __shared__ unsigned short Bs[128 * 128];   // 32 KB (Wt, swizzled rows n)
    __shared__ unsigned short As[64 * 128];    // 16 KB (A tile, swizzled rows r)
    const int t = threadIdx.x;
    const int m0 = blockIdx.x * 64;
    const int M = 2 * N;

    // stage Wt: straight 32KB copy (already swizzled)
    {
        const uint4* src = (const uint4*)Wt;
        uint4* dst = (uint4*)Bs;
        #pragma unroll
        for (int i = 0; i < 8; ++i) dst[t + 256 * i] = src[t + 256 * i];
    }
    // stage A: 1024 x 16B blocks; fp32 -> bf16 convert, swizzled write
    #pragma unroll
    for (int i = 0; i < 4; ++i) {
        const int blk = t + 256 * i;
        const int r  = blk >> 4;          // 0..63
        const int k0 = (blk & 15) * 8;    // 0..120
        const int m  = m0 + r;
        float4 q0 = make_float4(0.f, 0.f, 0.f, 0.f);
        float4 q1 = make_float4(0.f, 0.f, 0.f, 0.f);
        if (m < M) {
            const float* src = (m < N) ? (Xr + (size_t)m * CC)
                                       : (Xi + (size_t)(m - N) * CC);
            q0 = *(const float4*)(src + k0);
            q1 = *(const float4*)(src + k0 + 4);
        }
        uint4 h;
        h.x = pack2(q0.x, q0.y);
        h.y = pack2(q0.z, q0.w);
        h.z = pack2(q1.x, q1.y);
        h.w = pack2(q1.z, q1.w);
        const int byte = r * 256 + ((2 * k0) ^ ((r & 7) << 4));
        *(uint4*)((char*)As + byte) = h;
    }
    __syncthreads();

    const int w = t >> 6, lane = t & 63;
    const int wr = w >> 1, wc = w & 1;     // 2x2 wave grid
    const int r0 = wr * 32;                // local row base (32 rows/wave)
    const int c0 = wc * 64;                // local col base (64 cols/wave)
    const int lr = lane & 15;              // frag row/col index
    const int lk = lane >> 4;              // k-group (0..3)

    f32x4 acc[2][4];
    #pragma unroll
    for (int a = 0; a < 2; ++a)
        #pragma unroll
        for (int b = 0; b < 4; ++b)
            acc[a][b] = (f32x4){0.f, 0.f, 0.f, 0.f};

    #pragma unroll
    for (int kk = 0; kk < 4; ++kk) {
        const int kbase = kk * 32 + lk * 8;
        bf16x8 afrag[2];
        #pragma unroll
        for (int at = 0; at < 2; ++at) {
            const int row = r0 + at * 16 + lr;
            afrag[at] = *(const bf16x8*)((const char*)As +
                row * 256 + ((2 * kbase) ^ ((row & 7) << 4)));
        }
        #pragma unroll
        for (int bt = 0; bt < 4; ++bt) {
            const int col = c0 + bt * 16 + lr;
            const bf16x8 bfrag = *(const bf16x8*)((const char*)Bs +
                col * 256 + ((2 * kbase) ^ ((col & 7) << 4)));
            acc[0][bt] = __builtin_amdgcn_mfma_f32_16x16x32_bf16(
                afrag[0], bfrag, acc[0][bt], 0, 0, 0);
            acc[1][bt] = __builtin_amdgcn_mfma_f32_16x16x32_bf16(
                afrag[1], bfrag, acc[1][bt], 0, 0, 0);
        }
    }

    // store: C/D lane mapping col=lane&15, row=(lane>>4)*4+v
    #pragma unroll
    for (int at = 0; at < 2; ++at) {
        #pragma unroll
        for (int v = 0; v < 4; ++v) {
            const int m = m0 + r0 + at * 16 + lk * 4 + v;
            if (m >= M) continue;
            const int node = (m < N) ? m : m - N;
            const int half = (m < N) ? 0 : 128;
            unsigned short* dst = Y + (size_t)node * 256 + half;
            #pragma unroll
            for (int bt = 0; bt < 4; ++bt)
                dst[c0 + bt * 16 + lr] = f2bf(acc[at][bt][v]);
        }
    }
}

// ===========================================================================
// Fused gather: out[n] = sum_e L_e * Ybf16[col_e] + X[n]  (complex),
// 1 wave/node, 2 ch/lane, 8-edge chunks. (verified, 74us; offsets == rbase[0])
// ===========================================================================
__device__ __forceinline__ void cmadd_bf(
    const int4 m, const unsigned int ur, const unsigned int ui,
    float2& aR, float2& aI)
{
    const float lr = __int_as_float(m.y);
    const float li = __int_as_float(m.z);
    const float yrx = __uint_as_float(ur << 16);
    const float yry = __uint_as_float(ur & 0xFFFF0000u);
    const float yix = __uint_as_float(ui << 16);
    const float yiy = __uint_as_float(ui & 0xFFFF0000u);
    aR.x += lr * yrx - li * yix;
    aR.y += lr * yry - li * yiy;
    aI.x += li * yrx + lr * yix;
    aI.y += li * yry + lr * yiy;
}

__device__ __forceinline__ void edge_acc(
    const int4 m, const unsigned short* __restrict__ Y,
    int lane, float2& aR, float2& aI)
{
    const unsigned short* b = Y + (size_t)m.x * 256 + 2 * lane;
    const unsigned int ur = *(const unsigned int*)(b);
    const unsigned int ui = *(const unsigned int*)(b + 128);
    cmadd_bf(m, ur, ui, aR, aI);
}

__global__ __launch_bounds__(256) void gather_fused(
    const unsigned short* __restrict__ Y,  // packed bf16 [N][256]
    const float* __restrict__ Xr, const float* __restrict__ Xi,
    const int* __restrict__ offsets, const int4* __restrict__ meta,
    float* __restrict__ out, int N, int E)
{
    const int n = blockIdx.x * 4 + (threadIdx.x >> 6);
    if (n >= N) return;
    const int lane = threadIdx.x & 63;
    const int start = offsets[n];
    const int end   = (n + 1 < N) ? offsets[n + 1] : E;
    const int Em1 = E - 1;

    // residual init
    float2 aR = *(const float2*)(Xr + (size_t)n * CC + 2 * lane);
    float2 aI = *(const float2*)(Xi + (size_t)n * CC + 2 * lane);

    int4 m0 = meta[min(start + 0, Em1)];
    int4 m1 = meta[min(start + 1, Em1)];
    int4 m2 = meta[min(start + 2, Em1)];
    int4 m3 = meta[min(start + 3, Em1)];
    int4 m4 = meta[min(start + 4, Em1)];
    int4 m5 = meta[min(start + 5, Em1)];
    int4 m6 = meta[min(start + 6, Em1)];
    int4 m7 = meta[min(start + 7, Em1)];

    int j = start;
    for (; j + 8 <= end; j += 8) {
        // prefetch next chunk's meta (wave-uniform)
        const int4 n0 = meta[min(j +  8, Em1)];
        const int4 n1 = meta[min(j +  9, Em1)];
        const int4 n2 = meta[min(j + 10, Em1)];
        const int4 n3 = meta[min(j + 11, Em1)];
        const int4 n4 = meta[min(j + 12, Em1)];
        const int4 n5 = meta[min(j + 13, Em1)];
        const int4 n6 = meta[min(j + 14, Em1)];
        const int4 n7 = meta[min(j + 15, Em1)];
        // 16 independent dword loads from 8 contiguous 512B rows
        const unsigned short* b0 = Y + (size_t)m0.x * 256 + 2 * lane;
        const unsigned short* b1 = Y + (size_t)m1.x * 256 + 2 * lane;
        const unsigned short* b2 = Y + (size_t)m2.x * 256 + 2 * lane;
        const unsigned short* b3 = Y + (size_t)m3.x * 256 + 2 * lane;
        const unsigned short* b4 = Y + (size_t)m4.x * 256 + 2 * lane;
        const unsigned short* b5 = Y + (size_t)m5.x * 256 + 2 * lane;
        const unsigned short* b6 = Y + (size_t)m6.x * 256 + 2 * lane;
        const unsigned short* b7 = Y + (size_t)m7.x * 256 + 2 * lane;
        const unsigned int ur0 = *(const unsigned int*)(b0);
        const unsigned int ui0 = *(const unsigned int*)(b0 + 128);
        const unsigned int ur1 = *(const unsigned int*)(b1);
        const unsigned int ui1 = *(const unsigned int*)(b1 + 128);
        const unsigned int ur2 = *(const unsigned int*)(b2);
        const unsigned int ui2 = *(const unsigned int*)(b2 + 128);
        const unsigned int ur3 = *(const unsigned int*)(b3);
        const unsigned int ui3 = *(const unsigned int*)(b3 + 128);
        const unsigned int ur4 = *(const unsigned int*)(b4);
        const unsigned int ui4 = *(const unsigned int*)(b4 + 128);
        const unsigned int ur5 = *(const unsigned int*)(b5);
        const unsigned int ui5 = *(const unsigned int*)(b5 + 128);
        const unsigned int ur6 = *(const unsigned int*)(b6);
        const unsigned int ui6 = *(const unsigned int*)(b6 + 128);
        const unsigned int ur7 = *(const unsigned int*)(b7);
        const unsigned int ui7 = *(const unsigned int*)(b7 + 128);

        cmadd_bf(m0, ur0, ui0, aR, aI);
        cmadd_bf(m1, ur1, ui1, aR, aI);
        cmadd_bf(m2, ur2, ui2, aR, aI);
        cmadd_bf(m3, ur3, ui3, aR, aI);
        cmadd_bf(m4, ur4, ui4, aR, aI);
        cmadd_bf(m5, ur5, ui5, aR, aI);
        cmadd_bf(m6, ur6, ui6, aR, aI);
        cmadd_bf(m7, ur7, ui7, aR, aI);

        m0 = n0; m1 = n1; m2 = n2; m3 = n3;
        m4 = n4; m5 = n5; m6 = n6; m7 = n7;
    }
    const int r = end - j;   // 0..7 remaining edges, meta already in m0..m6
    if (r > 0) edge_acc(m0, Y, lane, aR, aI);
    if (r > 1) edge_acc(m1, Y, lane, aR, aI);
    if (r > 2) edge_acc(m2, Y, lane, aR, aI);
    if (r > 3) edge_acc(m3, Y, lane, aR, aI);
    if (r > 4) edge_acc(m4, Y, lane, aR, aI);
    if (r > 5) edge_acc(m5, Y, lane, aR, aI);
    if (r > 6) edge_acc(m6, Y, lane, aR, aI);

    *(float2*)(out + (size_t)n * CC + 2 * lane) = aR;
    *(float2*)(out + ((size_t)n + N) * CC + 2 * lane) = aI;
}

// ===========================================================================
// Fallback kernels (full fp32 paths)
// ===========================================================================
__global__ __launch_bounds__(256) void gather_nodes(
    const float* __restrict__ Xr, const float* __restrict__ Xi,
    const int* __restrict__ offsets, const int4* __restrict__ meta,
    float* __restrict__ out, int N, int E)
{
    const int n = blockIdx.x * 4 + (threadIdx.x >> 6);
    if (n >= N) return;
    const int lane = threadIdx.x & 63;
    const int start = offsets[n];
    const int end   = (n + 1 < N) ? offsets[n + 1] : E;
    float2 aR = make_float2(0.f, 0.f);
    float2 aI = make_float2(0.f, 0.f);
    for (int j = start; j < end; ++j) {
        const int4 m0 = meta[j];
        const float2 xr0 = *(const float2*)(Xr + (size_t)m0.x * CC + 2 * lane);
        const float2 xi0 = *(const float2*)(Xi + (size_t)m0.x * CC + 2 * lane);
        const float lr0 = __int_as_float(m0.y), li0 = __int_as_float(m0.z);
        aR.x += lr0 * xr0.x - li0 * xi0.x;
        aR.y += lr0 * xr0.y - li0 * xi0.y;
        aI.x += li0 * xr0.x + lr0 * xi0.x;
        aI.y += li0 * xr0.y + lr0 * xi0.y;
    }
    *(float2*)(out + (size_t)n * CC + 2 * lane) = aR;
    *(float2*)(out + ((size_t)n + N) * CC + 2 * lane) = aI;
}

__global__ __launch_bounds__(256) void scatter_edges(
    const float* __restrict__ Xr, const float* __restrict__ Xi,
    const float* __restrict__ Lr, const float* __restrict__ Li,
    const int* __restrict__ row, const int* __restrict__ col,
    float* __restrict__ out, int N, int E)
{
    const int e = blockIdx.x * 4 + (threadIdx.x >> 6);
    if (e >= E) return;
    const int lane = threadIdx.x & 63;
    const int r = row[e], c = col[e];
    const float lr = Lr[e];
    const float li = Li[e];
    const float2 xr = *(const float2*)(Xr + (size_t)c * CC + 2 * lane);
    const float2 xi = *(const float2*)(Xi + (size_t)c * CC + 2 * lane);
    float* pr = out + (size_t)r * CC + 2 * lane;
    float* pi = out + ((size_t)r + N) * CC + 2 * lane;
    unsafeAtomicAdd(pr,     lr * xr.x - li * xi.x);
    unsafeAtomicAdd(pr + 1, lr * xr.y - li * xi.y);
    unsafeAtomicAdd(pi,     li * xr.x + lr * xi.x);
    unsafeAtomicAdd(pi + 1, li * xr.y + lr * xi.y);
}

__global__ __launch_bounds__(256) void gemm_inplace(
    float* __restrict__ io, const float* __restrict__ W,
    const float* __restrict__ Xp, int N)
{
    __shared__ float Ws[64 * CC];
    __shared__ float AsT[CC][36];
    const int t = threadIdx.x;
    const int m0 = blockIdx.x * 32;

    for (int ch = t; ch < 1024; ch += 256) {
        const int r  = ch >> 5;
        const int k0 = (ch & 31) * 4;
        const int m  = m0 + r;
        float4 q = make_float4(0.f, 0.f, 0.f, 0.f);
        if (m < N) q = *(const float4*)(io + (size_t)m * CC + k0);
        AsT[k0 + 0][r] = q.x;
        AsT[k0 + 1][r] = q.y;
        AsT[k0 + 2][r] = q.z;
        AsT[k0 + 3][r] = q.w;
    }

    const int cg = t & 31;
    const int rs = t >> 5;
    float s[4][4];
    #pragma unroll
    for (int a = 0; a < 4; ++a)
        #pragma unroll
        for (int b = 0; b < 4; ++b) s[a][b] = 0.f;

    for (int kc = 0; kc < 2; ++kc) {
        __syncthreads();
        {
            const float4* src = (const float4*)(W + (size_t)kc * 64 * CC);
            float4* dst = (float4*)Ws;
            #pragma unroll
            for (int i = 0; i < 8; ++i) dst[t + 256 * i] = src[t + 256 * i];
        }
        __syncthreads();
        #pragma unroll 4
        for (int kk = 0; kk < 64; ++kk) {
            const int k = kc * 64 + kk;
            const float4 av = *(const float4*)&AsT[k][rs * 4];
            const float4 wv = *(const float4*)&Ws[kk * CC + cg * 4];
            const float ar[4] = {av.x, av.y, av.z, av.w};
            const float wc[4] = {wv.x, wv.y, wv.z, wv.w};
            #pragma unroll
            for (int a = 0; a < 4; ++a)
                #pragma unroll
                for (int b = 0; b < 4; ++b) s[a][b] += ar[a] * wc[b];
        }
    }

    #pragma unroll
    for (int a = 0; a < 4; ++a) {
        const int m = m0 + rs * 4 + a;
        if (m >= N) continue;
        const float4 xv = *(const float4*)(Xp + (size_t)m * CC + cg * 4);
        float4 o;
        o.x = s[a][0] + xv.x;
        o.y = s[a][1] + xv.y;
        o.z = s[a][2] + xv.z;
        o.w = s[a][3] + xv.w;
        *(float4*)(io + (size_t)m * CC + cg * 4) = o;
    }
}

// ===========================================================================
extern "C" void kernel_launch(void* const* d_in, const int* in_sizes, int n_in,
                              void* d_out, int out_size, void* d_ws, size_t ws_size,
                              hipStream_t stream)
{
    const float* Xr = (const float*)d_in[0];
    const float* Xi = (const float*)d_in[1];
    const float* Lr = (const float*)d_in[2];
    const float* Li = (const float*)d_in[3];
    const float* W  = (const float*)d_in[4];
    const int* row = (const int*)d_in[5];
    const int* col = (const int*)d_in[6];
    float* out = (float*)d_out;

    const int N = in_sizes[0] / CC;     // 50000
    const int E = in_sizes[2];          // 800000
    const int NB = (N + 255) / 256;     // scan blocks (196 <= 256)
    const int EB4 = ((E + 3) / 4 + 255) / 256;  // 4-edge/thread grids

    const size_t y_bytes    = (size_t)N * 256 * sizeof(unsigned short); // bf16 packed
    const size_t wt_bytes   = (size_t)CC * CC * sizeof(unsigned short); // 32 KB
    const size_t meta_bytes = (size_t)E * 16;
    // counts[4N] + rbase[4N] + bsum/bpre[512] + rank[E]
    const size_t int_bytes  = ((size_t)8 * N + 512 + E) * sizeof(int);
    const size_t need_csr   = meta_bytes + int_bytes;
    const size_t need_fused = y_bytes + wt_bytes + need_csr;

    if (ws_size >= need_fused) {
        unsigned short* Y  = (unsigned short*)d_ws;
        unsigned short* Wt = (unsigned short*)((char*)d_ws + y_bytes);
        int4*  meta   = (int4*)((char*)d_ws + y_bytes + wt_bytes);
        int*   counts = (int*)((char*)d_ws + y_bytes + wt_bytes + meta_bytes);
        int*   rbase  = counts + 4 * N;
        int*   bsum   = rbase + 4 * N;
        int*   bpre   = bsum + 256;
        int*   rank   = bpre + 256;

        hipMemsetAsync(counts, 0, (size_t)4 * N * sizeof(int), stream);
        hist_rank<<<dim3(EB4), dim3(256), 0, stream>>>(row, counts, rank, N, E);
        scan_block_reduce<<<dim3(NB), dim3(256), 0, stream>>>(counts, bsum, N);
        scan_bsum<<<dim3(1), dim3(256), 0, stream>>>(bsum, bpre, NB);
        scan_final<<<dim3(NB), dim3(256), 0, stream>>>(counts, bpre, rbase, N);
        fill_csr_rank<<<dim3(EB4), dim3(256), 0, stream>>>(
            row, col, Lr, Li, rbase, rank, meta, N, E);
        conv_w<<<dim3((CC * CC + 255) / 256), dim3(256), 0, stream>>>(W, Wt);
        gemm_xw_mfma<<<dim3((2 * N + 63) / 64), dim3(256), 0, stream>>>(
            Xr, Xi, Wt, Y, N);
        gather_fused<<<dim3((N + 3) / 4), dim3(256), 0, stream>>>(
            Y, Xr, Xi, rbase /* == offsets */, meta, out, N, E);
    } else if (ws_size >= need_csr) {
        int4* meta    = (int4*)d_ws;
        int*  counts  = (int*)((char*)d_ws + meta_bytes);
        int*  rbase   = counts + 4 * N;
        int*  bsum    = rbase + 4 * N;
        int*  bpre    = bsum + 256;
        int*  rank    = bpre + 256;

        hipMemsetAsync(counts, 0, (size_t)4 * N * sizeof(int), stream);
        hist_rank<<<dim3(EB4), dim3(256), 0, stream>>>(row, counts, rank, N, E);
        scan_block_reduce<<<dim3(NB), dim3(256), 0, stream>>>(counts, bsum, N);
        scan_bsum<<<dim3(1), dim3(256), 0, stream>>>(bsum, bpre, NB);
        scan_final<<<dim3(NB), dim3(256), 0, stream>>>(counts, bpre, rbase, N);
        fill_csr_rank<<<dim3(EB4), dim3(256), 0, stream>>>(
            row, col, Lr, Li, rbase, rank, meta, N, E);
        gather_nodes<<<dim3((N + 3) / 4), dim3(256), 0, stream>>>(
            Xr, Xi, rbase, meta, out, N, E);
        gemm_inplace<<<dim3((N + 31) / 32), dim3(256), 0, stream>>>(out, W, Xr, N);
        gemm_inplace<<<dim3((N + 31) / 32), dim3(256), 0, stream>>>(
            out + (size_t)N * CC, W, Xi, N);
    } else {
        hipMemsetAsync(out, 0, (size_t)2 * N * CC * sizeof(float), stream);
        scatter_edges<<<dim3((E + 3) / 4), dim3(256), 0, stream>>>(
            Xr, Xi, Lr, Li, row, col, out, N, E);
        gemm_inplace<<<dim3((N + 31) / 32), dim3(256), 0, stream>>>(out, W, Xr, N);
        gemm_inplace<<<dim3((N + 31) / 32), dim3(256), 0, stream>>>(
            out + (size_t)N * CC, W, Xi, N);
    }
}

// Round 11
// 247.020 us; speedup vs baseline: 1.5963x; 1.0180x over previous
//
#include <hip/hip_runtime.h>
#include <cstddef>

#define CC 128  // channels

typedef __attribute__((ext_vector_type(8))) short bf16x8;
typedef __attribute__((ext_vector_type(4))) float f32x4;

// ===========================================================================
// CSR build: 4-bank histogram(+rank) -> scan (+replica bases) -> atomic-free
// fill. pos = rbase[e&3][row] + rank[e]; rbase[0] IS the offsets array.
// Independent kernels are BLOCK-PARTITION FUSED for overlap (events are
// forbidden under graph capture, so no multi-stream): conv_w rides with
// hist_rank; gemm_xw_mfma rides with fill_csr_rank.
// ===========================================================================

// fp32 -> bf16 (round-to-nearest-even on the bit pattern)
__device__ __forceinline__ unsigned short f2bf(float f)
{
    unsigned int u = __float_as_uint(f);
    u = (u + 0x7fffu + ((u >> 16) & 1u)) >> 16;
    return (unsigned short)u;
}

__device__ __forceinline__ unsigned int pack2(float a, float b)
{
    return (unsigned int)f2bf(a) | ((unsigned int)f2bf(b) << 16);
}

// ---------------------------------------------------------------------------
// hist_rank + conv_w fused (both depend only on inputs).
// conv: Wt[n][k] = bf16(W[k][n]), pre-swizzled for LDS b128 reads.
// hist: 4 edges/thread, bank (e&3) -> rank = atomicAdd return.
// ---------------------------------------------------------------------------
__global__ __launch_bounds__(256) void hist_conv_fused(
    const int* __restrict__ row, int* __restrict__ counts,  // [4][N]
    int* __restrict__ rank, int N, int E,
    const float* __restrict__ W, unsigned short* __restrict__ Wt, int G_conv)
{
    const int bid = blockIdx.x;
    if (bid < G_conv) {
        const int idx = bid * 256 + threadIdx.x;
        if (idx >= CC * CC) return;
        const int k = idx >> 7;          // coalesced read of W[k][n]
        const int n = idx & 127;
        const unsigned int sw =
            ((unsigned)(2 * k) ^ (((unsigned)n & 7u) << 4)) >> 1;
        Wt[(size_t)n * 128 + sw] = f2bf(W[idx]);
        return;
    }
    const int base = ((bid - G_conv) * 256 + threadIdx.x) * 4;
    if (base + 3 < E) {
        const int4 r4 = *(const int4*)(row + base);
        int4 k4;
        k4.x = atomicAdd(counts + 0 * N + r4.x, 1);
        k4.y = atomicAdd(counts + 1 * N + r4.y, 1);
        k4.z = atomicAdd(counts + 2 * N + r4.z, 1);
        k4.w = atomicAdd(counts + 3 * N + r4.w, 1);
        *(int4*)(rank + base) = k4;
    } else {
        for (int e = base; e < E; ++e)
            rank[e] = atomicAdd(counts + (size_t)(e & 3) * N + row[e], 1);
    }
}

// Per-block sum of 256 row-totals (4 banks summed) -> bsum[block]
__global__ __launch_bounds__(256) void scan_block_reduce(
    const int* __restrict__ counts, int* __restrict__ bsum, int N)
{
    __shared__ int s[256];
    const int t = threadIdx.x;
    const int idx = blockIdx.x * 256 + t;
    int v = 0;
    if (idx < N)
        v = counts[idx] + counts[N + idx] + counts[2 * N + idx]
          + counts[3 * N + idx];
    s[t] = v;
    __syncthreads();
    #pragma unroll
    for (int off = 128; off > 0; off >>= 1) {
        if (t < off) s[t] += s[t + off];
        __syncthreads();
    }
    if (t == 0) bsum[blockIdx.x] = s[0];
}

// Exclusive scan of NB (<=256) block sums, single block.
__global__ __launch_bounds__(256) void scan_bsum(
    const int* __restrict__ bsum, int* __restrict__ bpre, int NB)
{
    __shared__ int s[256];
    const int t = threadIdx.x;
    s[t] = (t < NB) ? bsum[t] : 0;
    __syncthreads();
    #pragma unroll
    for (int off = 1; off < 256; off <<= 1) {
        const int v = s[t];
        const int u = (t >= off) ? s[t - off] : 0;
        __syncthreads();
        s[t] = v + u;
        __syncthreads();
    }
    if (t < NB) bpre[t] = t ? s[t - 1] : 0;
}

// Block-local exclusive scan of row totals + block prefix -> replica bases.
__global__ __launch_bounds__(256) void scan_final(
    const int* __restrict__ counts, const int* __restrict__ bpre,
    int* __restrict__ rbase, int N)
{
    __shared__ int s[256];
    const int t = threadIdx.x;
    const int idx = blockIdx.x * 256 + t;
    int c0 = 0, c1 = 0, c2 = 0, c3 = 0;
    if (idx < N) {
        c0 = counts[idx];
        c1 = counts[N + idx];
        c2 = counts[2 * N + idx];
        c3 = counts[3 * N + idx];
    }
    const int v = c0 + c1 + c2 + c3;
    s[t] = v;
    __syncthreads();
    #pragma unroll
    for (int off = 1; off < 256; off <<= 1) {
        const int a = s[t];
        const int u = (t >= off) ? s[t - off] : 0;
        __syncthreads();
        s[t] = a + u;
        __syncthreads();
    }
    if (idx < N) {
        const int off = bpre[blockIdx.x] + s[t] - v;  // exclusive row start
        rbase[idx]         = off;
        rbase[N + idx]     = off + c0;
        rbase[2 * N + idx] = off + c0 + c1;
        rbase[3 * N + idx] = off + c0 + c1 + c2;
    }
}

// ---------------------------------------------------------------------------
// gemm body (R8/R9-verified): Y = [Xr;Xi] @ W via bf16 MFMA, Y packed bf16.
// ---------------------------------------------------------------------------
__device__ __forceinline__ void gemm_body(
    const float* __restrict__ Xr, const float* __restrict__ Xi,
    const unsigned short* __restrict__ Wt,
    unsigned short* __restrict__ Y, int N, int bid)
{
    __shared__ unsigned short Bs[128 * 128];   // 32 KB (Wt, swizzled rows n)
    __shared__ unsigned short As[64 * 128];    // 16 KB (A tile, swizzled rows r)
    const int t = threadIdx.x;
    const int m0 = bid * 64;
    const int M = 2 * N;

    {
        const uint4* src = (const uint4*)Wt;
        uint4* dst = (uint4*)Bs;
        #pragma unroll
        for (int i = 0; i < 8; ++i) dst[t + 256 * i] = src[t + 256 * i];
    }
    #pragma unroll
    for (int i = 0; i < 4; ++i) {
        const int blk = t + 256 * i;
        const int r  = blk >> 4;          // 0..63
        const int k0 = (blk & 15) * 8;    // 0..120
        const int m  = m0 + r;
        float4 q0 = make_float4(0.f, 0.f, 0.f, 0.f);
        float4 q1 = make_float4(0.f, 0.f, 0.f, 0.f);
        if (m < M) {
            const float* src = (m < N) ? (Xr + (size_t)m * CC)
                                       : (Xi + (size_t)(m - N) * CC);
            q0 = *(const float4*)(src + k0);
            q1 = *(const float4*)(src + k0 + 4);
        }
        uint4 h;
        h.x = pack2(q0.x, q0.y);
        h.y = pack2(q0.z, q0.w);
        h.z = pack2(q1.x, q1.y);
        h.w = pack2(q1.z, q1.w);
        const int byte = r * 256 + ((2 * k0) ^ ((r & 7) << 4));
        *(uint4*)((char*)As + byte) = h;
    }
    __syncthreads();

    const int w = t >> 6, lane = t & 63;
    const int wr = w >> 1, wc = w & 1;     // 2x2 wave grid
    const int r0 = wr * 32;
    const int c0 = wc * 64;
    const int lr = lane & 15;
    const int lk = lane >> 4;

    f32x4 acc[2][4];
    #pragma unroll
    for (int a = 0; a < 2; ++a)
        #pragma unroll
        for (int b = 0; b < 4; ++b)
            acc[a][b] = (f32x4){0.f, 0.f, 0.f, 0.f};

    #pragma unroll
    for (int kk = 0; kk < 4; ++kk) {
        const int kbase = kk * 32 + lk * 8;
        bf16x8 afrag[2];
        #pragma unroll
        for (int at = 0; at < 2; ++at) {
            const int row = r0 + at * 16 + lr;
            afrag[at] = *(const bf16x8*)((const char*)As +
                row * 256 + ((2 * kbase) ^ ((row & 7) << 4)));
        }
        #pragma unroll
        for (int bt = 0; bt < 4; ++bt) {
            const int col = c0 + bt * 16 + lr;
            const bf16x8 bfrag = *(const bf16x8*)((const char*)Bs +
                col * 256 + ((2 * kbase) ^ ((col & 7) << 4)));
            acc[0][bt] = __builtin_amdgcn_mfma_f32_16x16x32_bf16(
                afrag[0], bfrag, acc[0][bt], 0, 0, 0);
            acc[1][bt] = __builtin_amdgcn_mfma_f32_16x16x32_bf16(
                afrag[1], bfrag, acc[1][bt], 0, 0, 0);
        }
    }

    #pragma unroll
    for (int at = 0; at < 2; ++at) {
        #pragma unroll
        for (int v = 0; v < 4; ++v) {
            const int m = m0 + r0 + at * 16 + lk * 4 + v;
            if (m >= M) continue;
            const int node = (m < N) ? m : m - N;
            const int half = (m < N) ? 0 : 128;
            unsigned short* dst = Y + (size_t)node * 256 + half;
            #pragma unroll
            for (int bt = 0; bt < 4; ++bt)
                dst[c0 + bt * 16 + lr] = f2bf(acc[at][bt][v]);
        }
    }
}

// ---------------------------------------------------------------------------
// fill body (R9/R10-verified): atomic-free scatter, 4 edges/thread.
// ---------------------------------------------------------------------------
__device__ __forceinline__ void fill_body(
    const int* __restrict__ row, const int* __restrict__ col,
    const float* __restrict__ Lr, const float* __restrict__ Li,
    const int* __restrict__ rbase, const int* __restrict__ rank,
    int4* __restrict__ meta, int N, int E, int bid)
{
    const int base = (bid * 256 + threadIdx.x) * 4;
    if (base + 3 < E) {               // base%4==0 -> reps are exactly 0,1,2,3
        const int4   r4 = *(const int4*)(row + base);
        const int4   c4 = *(const int4*)(col + base);
        const float4 a4 = *(const float4*)(Lr + base);
        const float4 b4 = *(const float4*)(Li + base);
        const int4   k4 = *(const int4*)(rank + base);
        meta[rbase[r4.x] + k4.x] =
            make_int4(c4.x, __float_as_int(a4.x), __float_as_int(b4.x), 0);
        meta[rbase[N + r4.y] + k4.y] =
            make_int4(c4.y, __float_as_int(a4.y), __float_as_int(b4.y), 0);
        meta[rbase[2 * N + r4.z] + k4.z] =
            make_int4(c4.z, __float_as_int(a4.z), __float_as_int(b4.z), 0);
        meta[rbase[3 * N + r4.w] + k4.w] =
            make_int4(c4.w, __float_as_int(a4.w), __float_as_int(b4.w), 0);
    } else {
        for (int e = base; e < E; ++e)
            meta[rbase[(size_t)(e & 3) * N + row[e]] + rank[e]] =
                make_int4(col[e], __float_as_int(Lr[e]), __float_as_int(Li[e]), 0);
    }
}

// Fused: gemm blocks first (longest work starts earliest), then fill blocks.
// Both only depend on scan_final (fill) / inputs+Wt (gemm) -> safe overlap.
__global__ __launch_bounds__(256) void fill_gemm_fused(
    const int* __restrict__ row, const int* __restrict__ col,
    const float* __restrict__ Lr, const float* __restrict__ Li,
    const int* __restrict__ rbase, const int* __restrict__ rank,
    int4* __restrict__ meta,
    const float* __restrict__ Xr, const float* __restrict__ Xi,
    const unsigned short* __restrict__ Wt, unsigned short* __restrict__ Y,
    int N, int E, int G_gemm)
{
    const int bid = blockIdx.x;
    if (bid < G_gemm)
        gemm_body(Xr, Xi, Wt, Y, N, bid);
    else
        fill_body(row, col, Lr, Li, rbase, rank, meta, N, E, bid - G_gemm);
}

// ===========================================================================
// Fused gather: out[n] = sum_e L_e * Ybf16[col_e] + X[n]  (complex),
// 1 wave/node, 2 ch/lane, 8-edge chunks. (verified, 74us)
// ===========================================================================
__device__ __forceinline__ void cmadd_bf(
    const int4 m, const unsigned int ur, const unsigned int ui,
    float2& aR, float2& aI)
{
    const float lr = __int_as_float(m.y);
    const float li = __int_as_float(m.z);
    const float yrx = __uint_as_float(ur << 16);
    const float yry = __uint_as_float(ur & 0xFFFF0000u);
    const float yix = __uint_as_float(ui << 16);
    const float yiy = __uint_as_float(ui & 0xFFFF0000u);
    aR.x += lr * yrx - li * yix;
    aR.y += lr * yry - li * yiy;
    aI.x += li * yrx + lr * yix;
    aI.y += li * yry + lr * yiy;
}

__device__ __forceinline__ void edge_acc(
    const int4 m, const unsigned short* __restrict__ Y,
    int lane, float2& aR, float2& aI)
{
    const unsigned short* b = Y + (size_t)m.x * 256 + 2 * lane;
    const unsigned int ur = *(const unsigned int*)(b);
    const unsigned int ui = *(const unsigned int*)(b + 128);
    cmadd_bf(m, ur, ui, aR, aI);
}

__global__ __launch_bounds__(256) void gather_fused(
    const unsigned short* __restrict__ Y,  // packed bf16 [N][256]
    const float* __restrict__ Xr, const float* __restrict__ Xi,
    const int* __restrict__ offsets, const int4* __restrict__ meta,
    float* __restrict__ out, int N, int E)
{
    const int n = blockIdx.x * 4 + (threadIdx.x >> 6);
    if (n >= N) return;
    const int lane = threadIdx.x & 63;
    const int start = offsets[n];
    const int end   = (n + 1 < N) ? offsets[n + 1] : E;
    const int Em1 = E - 1;

    // residual init
    float2 aR = *(const float2*)(Xr + (size_t)n * CC + 2 * lane);
    float2 aI = *(const float2*)(Xi + (size_t)n * CC + 2 * lane);

    int4 m0 = meta[min(start + 0, Em1)];
    int4 m1 = meta[min(start + 1, Em1)];
    int4 m2 = meta[min(start + 2, Em1)];
    int4 m3 = meta[min(start + 3, Em1)];
    int4 m4 = meta[min(start + 4, Em1)];
    int4 m5 = meta[min(start + 5, Em1)];
    int4 m6 = meta[min(start + 6, Em1)];
    int4 m7 = meta[min(start + 7, Em1)];

    int j = start;
    for (; j + 8 <= end; j += 8) {
        // prefetch next chunk's meta (wave-uniform)
        const int4 n0 = meta[min(j +  8, Em1)];
        const int4 n1 = meta[min(j +  9, Em1)];
        const int4 n2 = meta[min(j + 10, Em1)];
        const int4 n3 = meta[min(j + 11, Em1)];
        const int4 n4 = meta[min(j + 12, Em1)];
        const int4 n5 = meta[min(j + 13, Em1)];
        const int4 n6 = meta[min(j + 14, Em1)];
        const int4 n7 = meta[min(j + 15, Em1)];
        // 16 independent dword loads from 8 contiguous 512B rows
        const unsigned short* b0 = Y + (size_t)m0.x * 256 + 2 * lane;
        const unsigned short* b1 = Y + (size_t)m1.x * 256 + 2 * lane;
        const unsigned short* b2 = Y + (size_t)m2.x * 256 + 2 * lane;
        const unsigned short* b3 = Y + (size_t)m3.x * 256 + 2 * lane;
        const unsigned short* b4 = Y + (size_t)m4.x * 256 + 2 * lane;
        const unsigned short* b5 = Y + (size_t)m5.x * 256 + 2 * lane;
        const unsigned short* b6 = Y + (size_t)m6.x * 256 + 2 * lane;
        const unsigned short* b7 = Y + (size_t)m7.x * 256 + 2 * lane;
        const unsigned int ur0 = *(const unsigned int*)(b0);
        const unsigned int ui0 = *(const unsigned int*)(b0 + 128);
        const unsigned int ur1 = *(const unsigned int*)(b1);
        const unsigned int ui1 = *(const unsigned int*)(b1 + 128);
        const unsigned int ur2 = *(const unsigned int*)(b2);
        const unsigned int ui2 = *(const unsigned int*)(b2 + 128);
        const unsigned int ur3 = *(const unsigned int*)(b3);
        const unsigned int ui3 = *(const unsigned int*)(b3 + 128);
        const unsigned int ur4 = *(const unsigned int*)(b4);
        const unsigned int ui4 = *(const unsigned int*)(b4 + 128);
        const unsigned int ur5 = *(const unsigned int*)(b5);
        const unsigned int ui5 = *(const unsigned int*)(b5 + 128);
        const unsigned int ur6 = *(const unsigned int*)(b6);
        const unsigned int ui6 = *(const unsigned int*)(b6 + 128);
        const unsigned int ur7 = *(const unsigned int*)(b7);
        const unsigned int ui7 = *(const unsigned int*)(b7 + 128);

        cmadd_bf(m0, ur0, ui0, aR, aI);
        cmadd_bf(m1, ur1, ui1, aR, aI);
        cmadd_bf(m2, ur2, ui2, aR, aI);
        cmadd_bf(m3, ur3, ui3, aR, aI);
        cmadd_bf(m4, ur4, ui4, aR, aI);
        cmadd_bf(m5, ur5, ui5, aR, aI);
        cmadd_bf(m6, ur6, ui6, aR, aI);
        cmadd_bf(m7, ur7, ui7, aR, aI);

        m0 = n0; m1 = n1; m2 = n2; m3 = n3;
        m4 = n4; m5 = n5; m6 = n6; m7 = n7;
    }
    const int r = end - j;   // 0..7 remaining edges, meta already in m0..m6
    if (r > 0) edge_acc(m0, Y, lane, aR, aI);
    if (r > 1) edge_acc(m1, Y, lane, aR, aI);
    if (r > 2) edge_acc(m2, Y, lane, aR, aI);
    if (r > 3) edge_acc(m3, Y, lane, aR, aI);
    if (r > 4) edge_acc(m4, Y, lane, aR, aI);
    if (r > 5) edge_acc(m5, Y, lane, aR, aI);
    if (r > 6) edge_acc(m6, Y, lane, aR, aI);

    *(float2*)(out + (size_t)n * CC + 2 * lane) = aR;
    *(float2*)(out + ((size_t)n + N) * CC + 2 * lane) = aI;
}

// ===========================================================================
// Fallback kernels (full fp32 paths)
// ===========================================================================
__global__ __launch_bounds__(256) void gather_nodes(
    const float* __restrict__ Xr, const float* __restrict__ Xi,
    const int* __restrict__ offsets, const int4* __restrict__ meta,
    float* __restrict__ out, int N, int E)
{
    const int n = blockIdx.x * 4 + (threadIdx.x >> 6);
    if (n >= N) return;
    const int lane = threadIdx.x & 63;
    const int start = offsets[n];
    const int end   = (n + 1 < N) ? offsets[n + 1] : E;
    float2 aR = make_float2(0.f, 0.f);
    float2 aI = make_float2(0.f, 0.f);
    for (int j = start; j < end; ++j) {
        const int4 m0 = meta[j];
        const float2 xr0 = *(const float2*)(Xr + (size_t)m0.x * CC + 2 * lane);
        const float2 xi0 = *(const float2*)(Xi + (size_t)m0.x * CC + 2 * lane);
        const float lr0 = __int_as_float(m0.y), li0 = __int_as_float(m0.z);
        aR.x += lr0 * xr0.x - li0 * xi0.x;
        aR.y += lr0 * xr0.y - li0 * xi0.y;
        aI.x += li0 * xr0.x + lr0 * xi0.x;
        aI.y += li0 * xr0.y + lr0 * xi0.y;
    }
    *(float2*)(out + (size_t)n * CC + 2 * lane) = aR;
    *(float2*)(out + ((size_t)n + N) * CC + 2 * lane) = aI;
}

__global__ __launch_bounds__(256) void scatter_edges(
    const float* __restrict__ Xr, const float* __restrict__ Xi,
    const float* __restrict__ Lr, const float* __restrict__ Li,
    const int* __restrict__ row, const int* __restrict__ col,
    float* __restrict__ out, int N, int E)
{
    const int e = blockIdx.x * 4 + (threadIdx.x >> 6);
    if (e >= E) return;
    const int lane = threadIdx.x & 63;
    const int r = row[e], c = col[e];
    const float lr = Lr[e];
    const float li = Li[e];
    const float2 xr = *(const float2*)(Xr + (size_t)c * CC + 2 * lane);
    const float2 xi = *(const float2*)(Xi + (size_t)c * CC + 2 * lane);
    float* pr = out + (size_t)r * CC + 2 * lane;
    float* pi = out + ((size_t)r + N) * CC + 2 * lane;
    unsafeAtomicAdd(pr,     lr * xr.x - li * xi.x);
    unsafeAtomicAdd(pr + 1, lr * xr.y - li * xi.y);
    unsafeAtomicAdd(pi,     li * xr.x + lr * xi.x);
    unsafeAtomicAdd(pi + 1, li * xr.y + lr * xi.y);
}

__global__ __launch_bounds__(256) void hist_rank_fb(
    const int* __restrict__ row, int* __restrict__ counts,
    int* __restrict__ rank, int N, int E)
{
    const int base = (blockIdx.x * 256 + threadIdx.x) * 4;
    if (base + 3 < E) {
        const int4 r4 = *(const int4*)(row + base);
        int4 k4;
        k4.x = atomicAdd(counts + 0 * N + r4.x, 1);
        k4.y = atomicAdd(counts + 1 * N + r4.y, 1);
        k4.z = atomicAdd(counts + 2 * N + r4.z, 1);
        k4.w = atomicAdd(counts + 3 * N + r4.w, 1);
        *(int4*)(rank + base) = k4;
    } else {
        for (int e = base; e < E; ++e)
            rank[e] = atomicAdd(counts + (size_t)(e & 3) * N + row[e], 1);
    }
}

__global__ __launch_bounds__(256) void fill_csr_fb(
    const int* __restrict__ row, const int* __restrict__ col,
    const float* __restrict__ Lr, const float* __restrict__ Li,
    const int* __restrict__ rbase, const int* __restrict__ rank,
    int4* __restrict__ meta, int N, int E)
{
    fill_body(row, col, Lr, Li, rbase, rank, meta, N, E, blockIdx.x);
}

__global__ __launch_bounds__(256) void gemm_inplace(
    float* __restrict__ io, const float* __restrict__ W,
    const float* __restrict__ Xp, int N)
{
    __shared__ float Ws[64 * CC];
    __shared__ float AsT[CC][36];
    const int t = threadIdx.x;
    const int m0 = blockIdx.x * 32;

    for (int ch = t; ch < 1024; ch += 256) {
        const int r  = ch >> 5;
        const int k0 = (ch & 31) * 4;
        const int m  = m0 + r;
        float4 q = make_float4(0.f, 0.f, 0.f, 0.f);
        if (m < N) q = *(const float4*)(io + (size_t)m * CC + k0);
        AsT[k0 + 0][r] = q.x;
        AsT[k0 + 1][r] = q.y;
        AsT[k0 + 2][r] = q.z;
        AsT[k0 + 3][r] = q.w;
    }

    const int cg = t & 31;
    const int rs = t >> 5;
    float s[4][4];
    #pragma unroll
    for (int a = 0; a < 4; ++a)
        #pragma unroll
        for (int b = 0; b < 4; ++b) s[a][b] = 0.f;

    for (int kc = 0; kc < 2; ++kc) {
        __syncthreads();
        {
            const float4* src = (const float4*)(W + (size_t)kc * 64 * CC);
            float4* dst = (float4*)Ws;
            #pragma unroll
            for (int i = 0; i < 8; ++i) dst[t + 256 * i] = src[t + 256 * i];
        }
        __syncthreads();
        #pragma unroll 4
        for (int kk = 0; kk < 64; ++kk) {
            const int k = kc * 64 + kk;
            const float4 av = *(const float4*)&AsT[k][rs * 4];
            const float4 wv = *(const float4*)&Ws[kk * CC + cg * 4];
            const float ar[4] = {av.x, av.y, av.z, av.w};
            const float wc[4] = {wv.x, wv.y, wv.z, wv.w};
            #pragma unroll
            for (int a = 0; a < 4; ++a)
                #pragma unroll
                for (int b = 0; b < 4; ++b) s[a][b] += ar[a] * wc[b];
        }
    }

    #pragma unroll
    for (int a = 0; a < 4; ++a) {
        const int m = m0 + rs * 4 + a;
        if (m >= N) continue;
        const float4 xv = *(const float4*)(Xp + (size_t)m * CC + cg * 4);
        float4 o;
        o.x = s[a][0] + xv.x;
        o.y = s[a][1] + xv.y;
        o.z = s[a][2] + xv.z;
        o.w = s[a][3] + xv.w;
        *(float4*)(io + (size_t)m * CC + cg * 4) = o;
    }
}

// ===========================================================================
extern "C" void kernel_launch(void* const* d_in, const int* in_sizes, int n_in,
                              void* d_out, int out_size, void* d_ws, size_t ws_size,
                              hipStream_t stream)
{
    const float* Xr = (const float*)d_in[0];
    const float* Xi = (const float*)d_in[1];
    const float* Lr = (const float*)d_in[2];
    const float* Li = (const float*)d_in[3];
    const float* W  = (const float*)d_in[4];
    const int* row = (const int*)d_in[5];
    const int* col = (const int*)d_in[6];
    float* out = (float*)d_out;

    const int N = in_sizes[0] / CC;     // 50000
    const int E = in_sizes[2];          // 800000
    const int NB = (N + 255) / 256;     // scan blocks (196 <= 256)
    const int EB4 = ((E + 3) / 4 + 255) / 256;  // 4-edge/thread grids
    const int G_conv = (CC * CC + 255) / 256;   // 64
    const int G_gemm = (2 * N + 63) / 64;       // 1563

    const size_t y_bytes    = (size_t)N * 256 * sizeof(unsigned short); // bf16 packed
    const size_t wt_bytes   = (size_t)CC * CC * sizeof(unsigned short); // 32 KB
    const size_t meta_bytes = (size_t)E * 16;
    // counts[4N] + rbase[4N] + bsum/bpre[512] + rank[E]
    const size_t int_bytes  = ((size_t)8 * N + 512 + E) * sizeof(int);
    const size_t need_csr   = meta_bytes + int_bytes;
    const size_t need_fused = y_bytes + wt_bytes + need_csr;

    if (ws_size >= need_fused) {
        unsigned short* Y  = (unsigned short*)d_ws;
        unsigned short* Wt = (unsigned short*)((char*)d_ws + y_bytes);
        int4*  meta   = (int4*)((char*)d_ws + y_bytes + wt_bytes);
        int*   counts = (int*)((char*)d_ws + y_bytes + wt_bytes + meta_bytes);
        int*   rbase  = counts + 4 * N;
        int*   bsum   = rbase + 4 * N;
        int*   bpre   = bsum + 256;
        int*   rank   = bpre + 256;

        hipMemsetAsync(counts, 0, (size_t)4 * N * sizeof(int), stream);
        hist_conv_fused<<<dim3(G_conv + EB4), dim3(256), 0, stream>>>(
            row, counts, rank, N, E, W, Wt, G_conv);
        scan_block_reduce<<<dim3(NB), dim3(256), 0, stream>>>(counts, bsum, N);
        scan_bsum<<<dim3(1), dim3(256), 0, stream>>>(bsum, bpre, NB);
        scan_final<<<dim3(NB), dim3(256), 0, stream>>>(counts, bpre, rbase, N);
        fill_gemm_fused<<<dim3(G_gemm + EB4), dim3(256), 0, stream>>>(
            row, col, Lr, Li, rbase, rank, meta, Xr, Xi, Wt, Y, N, E, G_gemm);
        gather_fused<<<dim3((N + 3) / 4), dim3(256), 0, stream>>>(
            Y, Xr, Xi, rbase /* == offsets */, meta, out, N, E);
    } else if (ws_size >= need_csr) {
        int4* meta    = (int4*)d_ws;
        int*  counts  = (int*)((char*)d_ws + meta_bytes);
        int*  rbase   = counts + 4 * N;
        int*  bsum    = rbase + 4 * N;
        int*  bpre    = bsum + 256;
        int*  rank    = bpre + 256;

        hipMemsetAsync(counts, 0, (size_t)4 * N * sizeof(int), stream);
        hist_rank_fb<<<dim3(EB4), dim3(256), 0, stream>>>(row, counts, rank, N, E);
        scan_block_reduce<<<dim3(NB), dim3(256), 0, stream>>>(counts, bsum, N);
        scan_bsum<<<dim3(1), dim3(256), 0, stream>>>(bsum, bpre, NB);
        scan_final<<<dim3(NB), dim3(256), 0, stream>>>(counts, bpre, rbase, N);
        fill_csr_fb<<<dim3(EB4), dim3(256), 0, stream>>>(
            row, col, Lr, Li, rbase, rank, meta, N, E);
        gather_nodes<<<dim3((N + 3) / 4), dim3(256), 0, stream>>>(
            Xr, Xi, rbase, meta, out, N, E);
        gemm_inplace<<<dim3((N + 31) / 32), dim3(256), 0, stream>>>(out, W, Xr, N);
        gemm_inplace<<<dim3((N + 31) / 32), dim3(256), 0, stream>>>(
            out + (size_t)N * CC, W, Xi, N);
    } else {
        hipMemsetAsync(out, 0, (size_t)2 * N * CC * sizeof(float), stream);
        scatter_edges<<<dim3((E + 3) / 4), dim3(256), 0, stream>>>(
            Xr, Xi, Lr, Li, row, col, out, N, E);
        gemm_inplace<<<dim3((N + 31) / 32), dim3(256), 0, stream>>>(out, W, Xr, N);
        gemm_inplace<<<dim3((N + 31) / 32), dim3(256), 0, stream>>>(
            out + (size_t)N * CC, W, Xi, N);
    }
}